// Round 7
// baseline (750.111 us; speedup 1.0000x reference)
//
#include <hip/hip_runtime.h>

#define N_NODES   100000
#define N_EDGES   1600000
#define NFEAT     128
#define N_GRAPHS  1024

// ---- bucketed CSR build ----
#define BSHIFT  6
#define NBUCK   1563                 // ceil(100000 / 64)
#define NSUB    8                    // sub-buckets (XCD-heuristic partition)
#define SUBCAP  256                  // mean 128, +11 sigma headroom
#define CURSTRIDE 16                 // one cursor per 64B line

typedef unsigned int uint32;
typedef unsigned short ushort;
typedef __attribute__((ext_vector_type(8))) short short8;   // 8 bf16 (4 VGPRs)
typedef __attribute__((ext_vector_type(4))) float f32x4;

// fp32 -> bf16 bits, round-to-nearest-even (finite inputs)
__device__ inline ushort f2b(float f) {
    uint32 x = __float_as_uint(f);
    uint32 r = x + 0x7fffu + ((x >> 16) & 1u);
    return (ushort)(r >> 16);
}
__device__ inline float b2f(ushort u) { return __uint_as_float((uint32)u << 16); }

// ---------------- phase 1: scatter edges into (bucket, sub) append regions ----------------
__global__ __launch_bounds__(256) void k_scatter(const int* __restrict__ src, const int* __restrict__ dst,
                                                 int* __restrict__ cur, uint32* __restrict__ bbuf) {
    int e = blockIdx.x * 256 + threadIdx.x;
    int sub = blockIdx.x & (NSUB - 1);
    if (e < N_EDGES) {
        int s = src[e], d = dst[e];
        int b = d >> BSHIFT;
        int slot = (b << 3) | sub;
        int p = atomicAdd(&cur[slot * CURSTRIDE], 1);
        if (p < SUBCAP)
            bbuf[slot * SUBCAP + p] = (uint32)(((d & 63) << 17) | s);
    }
}

// ---------------- exclusive scan of bucket totals -> bucketBase, + offsets[N] ----------------
__global__ __launch_bounds__(256) void k_bucketscan(const int* __restrict__ cur, int* __restrict__ bucketBase,
                                                    int* __restrict__ offsets) {
    __shared__ int wsum[4];
    int t = threadIdx.x;
    int v[7];
    int ts = 0;
    #pragma unroll
    for (int i = 0; i < 7; ++i) {
        int b = t * 7 + i;
        int sz = 0;
        if (b < NBUCK) {
            #pragma unroll
            for (int s = 0; s < NSUB; ++s) {
                int c = cur[((b << 3) | s) * CURSTRIDE];
                sz += (c < SUBCAP) ? c : SUBCAP;
            }
        }
        v[i] = sz;
        ts += sz;
    }
    int lane = t & 63, w = t >> 6;
    int inc = ts;
    #pragma unroll
    for (int d = 1; d < 64; d <<= 1) {
        int u = __shfl_up(inc, d, 64);
        if (lane >= d) inc += u;
    }
    if (lane == 63) wsum[w] = inc;
    __syncthreads();
    int wpre = 0;
    for (int i = 0; i < w; ++i) wpre += wsum[i];
    int run = wpre + inc - ts;
    #pragma unroll
    for (int i = 0; i < 7; ++i) {
        int b = t * 7 + i;
        if (b < NBUCK) bucketBase[b] = run;
        run += v[i];
    }
    if (t == 255) offsets[N_NODES] = run;   // == N_EDGES
}

// ---------------- phase 2: per-bucket local sort -> coalesced CSR + dinv + offsets ----------------
__global__ __launch_bounds__(256) void k_build(const uint32* __restrict__ bbuf, const int* __restrict__ cur,
                                               const int* __restrict__ bucketBase, int* __restrict__ col,
                                               int* __restrict__ offsets, float* __restrict__ dinv) {
    int b = blockIdx.x;
    __shared__ uint32 ebuf[NSUB * SUBCAP];    // 8 KB
    __shared__ int sorted[NSUB * SUBCAP];     // 8 KB
    __shared__ int hist[64], lcur[64];
    __shared__ int subOff[NSUB + 1];
    int t = threadIdx.x;
    if (t == 0) {
        int run = 0;
        #pragma unroll
        for (int s = 0; s < NSUB; ++s) {
            subOff[s] = run;
            int c = cur[((b << 3) | s) * CURSTRIDE];
            run += (c < SUBCAP) ? c : SUBCAP;
        }
        subOff[NSUB] = run;
    }
    if (t < 64) hist[t] = 0;
    __syncthreads();
    int cnt = subOff[NSUB];
    #pragma unroll
    for (int s = 0; s < NSUB; ++s) {
        int n = subOff[s + 1] - subOff[s];
        const uint32* p = bbuf + ((b << 3) | s) * SUBCAP;
        for (int i = t; i < n; i += 256) ebuf[subOff[s] + i] = p[i];
    }
    __syncthreads();
    for (int i = t; i < cnt; i += 256) atomicAdd(&hist[ebuf[i] >> 17], 1);
    __syncthreads();
    int nb = b << BSHIFT;
    if (t < 64) {   // wave 0: scan 64 counts, emit offsets + dinv
        int c = hist[t];
        int inc = c;
        #pragma unroll
        for (int d = 1; d < 64; d <<= 1) {
            int u = __shfl_up(inc, d, 64);
            if (t >= d) inc += u;
        }
        int excl = inc - c;
        lcur[t] = excl;
        int node = nb + t;
        if (node < N_NODES) {
            offsets[node] = bucketBase[b] + excl;
            dinv[node] = rsqrtf((float)(c + 1));
        }
    }
    __syncthreads();
    for (int i = t; i < cnt; i += 256) {
        uint32 p = ebuf[i];
        int lp = atomicAdd(&lcur[p >> 17], 1);
        sorted[lp] = (int)(p & 0x1FFFF);
    }
    __syncthreads();
    int base = bucketBase[b];
    for (int i = t; i < cnt; i += 256) col[base + i] = sorted[i];
}

// ---------------- cast + transpose W1,W2,W3 -> WT bf16 [layer][n][k] ----------------
__global__ __launch_bounds__(256) void k_castw(const float* __restrict__ W1, const float* __restrict__ W2,
                                               const float* __restrict__ W3, ushort* __restrict__ WT) {
    int i = blockIdx.x * blockDim.x + threadIdx.x;   // 3*16384
    if (i >= 3 * NFEAT * NFEAT) return;
    int l = i >> 14;
    int j = i & 16383;
    int n = j >> 7;
    int k = j & 127;
    const float* W = (l == 0) ? W1 : (l == 1) ? W2 : W3;
    WT[i] = f2b(W[k * NFEAT + n]);   // WT[l][n*128+k] = W[k][n]
}

// ---------------- bf16 MFMA GEMM: C[M,128] = A[M,128] @ W ----------------
#define WT_STRIDE 136
__global__ __launch_bounds__(256) void k_gemm(const ushort* __restrict__ A,
                                              const ushort* __restrict__ WTl,
                                              ushort* __restrict__ C, int M) {
    __shared__ ushort sWT[NFEAT * WT_STRIDE];   // 34 KB
    int t = threadIdx.x;
    for (int i = t; i < NFEAT * 16; i += 256) {
        int n = i >> 4, c = i & 15;
        *(float4*)(sWT + n * WT_STRIDE + c * 8) = ((const float4*)WTl)[i];
    }
    int wave = t >> 6, lane = t & 63;
    int m0 = blockIdx.x * 64 + wave * 16;
    int mRow = m0 + (lane & 15);
    if (mRow >= M) mRow = M - 1;
    int kg = lane >> 4;
    const short8* Ap = (const short8*)(A + (size_t)mRow * NFEAT + kg * 8);
    short8 a0 = Ap[0];
    short8 a1 = Ap[4];
    short8 a2 = Ap[8];
    short8 a3 = Ap[12];
    __syncthreads();

    f32x4 acc[8];
    #pragma unroll
    for (int nt = 0; nt < 8; ++nt) acc[nt] = (f32x4){0.f, 0.f, 0.f, 0.f};

    #pragma unroll
    for (int nt = 0; nt < 8; ++nt) {
        int n = nt * 16 + (lane & 15);
        const short8* Bp = (const short8*)(sWT + n * WT_STRIDE + kg * 8);
        short8 b0 = Bp[0];
        short8 b1 = Bp[4];
        short8 b2 = Bp[8];
        short8 b3 = Bp[12];
        acc[nt] = __builtin_amdgcn_mfma_f32_16x16x32_bf16(a0, b0, acc[nt], 0, 0, 0);
        acc[nt] = __builtin_amdgcn_mfma_f32_16x16x32_bf16(a1, b1, acc[nt], 0, 0, 0);
        acc[nt] = __builtin_amdgcn_mfma_f32_16x16x32_bf16(a2, b2, acc[nt], 0, 0, 0);
        acc[nt] = __builtin_amdgcn_mfma_f32_16x16x32_bf16(a3, b3, acc[nt], 0, 0, 0);
    }

    int colBase = lane & 15;
    #pragma unroll
    for (int r = 0; r < 4; ++r) {
        int gr = m0 + kg * 4 + r;
        if (gr < M) {
            ushort* Cp = C + (size_t)gr * NFEAT + colBase;
            #pragma unroll
            for (int nt = 0; nt < 8; ++nt) Cp[nt * 16] = f2b(acc[nt][r]);
        }
    }
}

// ---------------- same GEMM but A is fp32 (layer 1: fuses the x->bf16 cast) ----------------
__device__ inline short8 cvt8(const float* p) {
    float4 v0 = ((const float4*)p)[0];
    float4 v1 = ((const float4*)p)[1];
    short8 r;
    r[0] = (short)f2b(v0.x); r[1] = (short)f2b(v0.y);
    r[2] = (short)f2b(v0.z); r[3] = (short)f2b(v0.w);
    r[4] = (short)f2b(v1.x); r[5] = (short)f2b(v1.y);
    r[6] = (short)f2b(v1.z); r[7] = (short)f2b(v1.w);
    return r;
}

__global__ __launch_bounds__(256) void k_gemm_x(const float* __restrict__ A,
                                                const ushort* __restrict__ WTl,
                                                ushort* __restrict__ C, int M) {
    __shared__ ushort sWT[NFEAT * WT_STRIDE];   // 34 KB
    int t = threadIdx.x;
    for (int i = t; i < NFEAT * 16; i += 256) {
        int n = i >> 4, c = i & 15;
        *(float4*)(sWT + n * WT_STRIDE + c * 8) = ((const float4*)WTl)[i];
    }
    int wave = t >> 6, lane = t & 63;
    int m0 = blockIdx.x * 64 + wave * 16;
    int mRow = m0 + (lane & 15);
    if (mRow >= M) mRow = M - 1;
    int kg = lane >> 4;
    const float* Ap = A + (size_t)mRow * NFEAT + kg * 8;
    short8 a0 = cvt8(Ap);
    short8 a1 = cvt8(Ap + 32);
    short8 a2 = cvt8(Ap + 64);
    short8 a3 = cvt8(Ap + 96);
    __syncthreads();

    f32x4 acc[8];
    #pragma unroll
    for (int nt = 0; nt < 8; ++nt) acc[nt] = (f32x4){0.f, 0.f, 0.f, 0.f};

    #pragma unroll
    for (int nt = 0; nt < 8; ++nt) {
        int n = nt * 16 + (lane & 15);
        const short8* Bp = (const short8*)(sWT + n * WT_STRIDE + kg * 8);
        short8 b0 = Bp[0];
        short8 b1 = Bp[4];
        short8 b2 = Bp[8];
        short8 b3 = Bp[12];
        acc[nt] = __builtin_amdgcn_mfma_f32_16x16x32_bf16(a0, b0, acc[nt], 0, 0, 0);
        acc[nt] = __builtin_amdgcn_mfma_f32_16x16x32_bf16(a1, b1, acc[nt], 0, 0, 0);
        acc[nt] = __builtin_amdgcn_mfma_f32_16x16x32_bf16(a2, b2, acc[nt], 0, 0, 0);
        acc[nt] = __builtin_amdgcn_mfma_f32_16x16x32_bf16(a3, b3, acc[nt], 0, 0, 0);
    }

    int colBase = lane & 15;
    #pragma unroll
    for (int r = 0; r < 4; ++r) {
        int gr = m0 + kg * 4 + r;
        if (gr < M) {
            ushort* Cp = C + (size_t)gr * NFEAT + colBase;
            #pragma unroll
            for (int nt = 0; nt < 8; ++nt) Cp[nt * 16] = f2b(acc[nt][r]);
        }
    }
}

// ---------------- feature-split aggregation: one wave = one node's HALF row ----------------
// blockIdx%8 rides the round-robin XCD dispatch: XCD q only touches feature-half q&1,
// halving each XCD's gather working set (25.6 -> 12.8 MB).
// node = (b>>3)*16 + ((b&7)>>1)*4 + wave ; f = (b&1)*64 + lane.
#define AGG_H_BODY \
    float dn = dinv[n]; \
    const ushort* Xp = XWu + f; \
    float acc = dn * dn * b2f(XWu[(size_t)n * NFEAT + f]); \
    int e0 = off[n], e1 = off[n + 1]; \
    for (int base = e0; base < e1; base += 64) { \
        int len = e1 - base; if (len > 64) len = 64; \
        int cm = (lane < len) ? col[base + lane] : 0; \
        float wm = (lane < len) ? dn * dinv[cm] : 0.f; \
        int j = 0; \
        for (; j + 16 <= len; j += 16) { \
            float u[16]; \
            _Pragma("unroll") \
            for (int i = 0; i < 16; ++i) { \
                int cc = __shfl(cm, j + i, 64); \
                u[i] = b2f(Xp[(size_t)cc * NFEAT]); \
            } \
            _Pragma("unroll") \
            for (int i = 0; i < 16; ++i) { \
                float ww = __shfl(wm, j + i, 64); \
                acc = fmaf(ww, u[i], acc); \
            } \
        } \
        for (; j + 4 <= len; j += 4) { \
            float u[4]; \
            _Pragma("unroll") \
            for (int i = 0; i < 4; ++i) { \
                int cc = __shfl(cm, j + i, 64); \
                u[i] = b2f(Xp[(size_t)cc * NFEAT]); \
            } \
            _Pragma("unroll") \
            for (int i = 0; i < 4; ++i) { \
                float ww = __shfl(wm, j + i, 64); \
                acc = fmaf(ww, u[i], acc); \
            } \
        } \
        for (; j < len; ++j) { \
            int cc = __shfl(cm, j, 64); \
            float ww = __shfl(wm, j, 64); \
            acc = fmaf(ww, b2f(Xp[(size_t)cc * NFEAT]), acc); \
        } \
    }

__global__ __launch_bounds__(256) void k_agg_h(const ushort* __restrict__ XWu, const int* __restrict__ col,
                                               const int* __restrict__ off, const float* __restrict__ dinv,
                                               const float* __restrict__ bias, ushort* __restrict__ Hu) {
    int b = blockIdx.x;
    int q = b & 7;
    int wave = threadIdx.x >> 6, lane = threadIdx.x & 63;
    int n = (b >> 3) * 16 + (q >> 1) * 4 + wave;
    if (n >= N_NODES) return;
    int f = (q & 1) * 64 + lane;
    AGG_H_BODY
    float o = fmaxf(acc + bias[f], 0.f);
    Hu[(size_t)n * NFEAT + f] = f2b(o);
}

// layer-3: aggregation + relu + FC partial dot (per half) -> atomicAdd into nodeS
__global__ __launch_bounds__(256) void k_agg_fc_h(const ushort* __restrict__ XWu, const int* __restrict__ col,
                                                  const int* __restrict__ off, const float* __restrict__ dinv,
                                                  const float* __restrict__ bias, const float* __restrict__ Wfc,
                                                  float* __restrict__ nodeS) {
    int b = blockIdx.x;
    int q = b & 7;
    int wave = threadIdx.x >> 6, lane = threadIdx.x & 63;
    int n = (b >> 3) * 16 + (q >> 1) * 4 + wave;
    if (n >= N_NODES) return;
    int f = (q & 1) * 64 + lane;
    AGG_H_BODY
    float h = fmaxf(acc + bias[f], 0.f);
    float s = h * Wfc[f];
    for (int d = 32; d > 0; d >>= 1) s += __shfl_down(s, d, 64);
    if (lane == 0) atomicAdd(&nodeS[n], s);
}

// ---------------- segment mean over sorted batch + bias (one block per graph) ----------------
__device__ inline int lower_bound_dev(const int* a, int n, int key) {
    int lo = 0, hi = n;
    while (lo < hi) {
        int mid = (lo + hi) >> 1;
        if (a[mid] < key) lo = mid + 1; else hi = mid;
    }
    return lo;
}

__global__ __launch_bounds__(256) void k_pool(const float* __restrict__ nodeS, const int* __restrict__ batch,
                                              const float* __restrict__ bfc, float* __restrict__ out) {
    int g = blockIdx.x;
    int t = threadIdx.x;
    int lo = lower_bound_dev(batch, N_NODES, g);
    int hi = lower_bound_dev(batch, N_NODES, g + 1);
    float s = 0.f;
    for (int i = lo + t; i < hi; i += 256) s += nodeS[i];
    for (int d = 32; d > 0; d >>= 1) s += __shfl_down(s, d, 64);
    __shared__ float ws[4];
    int lane = t & 63, w = t >> 6;
    if (lane == 0) ws[w] = s;
    __syncthreads();
    if (t == 0) {
        float tot = ws[0] + ws[1] + ws[2] + ws[3];
        float cnt = (float)(hi - lo);
        out[g] = tot / fmaxf(cnt, 1.0f) + bfc[0];
    }
}

// ---------------- launch ----------------
extern "C" void kernel_launch(void* const* d_in, const int* in_sizes, int n_in,
                              void* d_out, int out_size, void* d_ws, size_t ws_size,
                              hipStream_t stream) {
    const float* x    = (const float*)d_in[0];
    const int*   ei   = (const int*)d_in[1];     // [2, E] : row0 = src, row1 = dst
    const int*   batch= (const int*)d_in[2];
    const float* W1   = (const float*)d_in[3];
    const float* b1   = (const float*)d_in[4];
    const float* W2   = (const float*)d_in[5];
    const float* b2   = (const float*)d_in[6];
    const float* W3   = (const float*)d_in[7];
    const float* b3   = (const float*)d_in[8];
    const float* Wfc  = (const float*)d_in[9];
    const float* bfc  = (const float*)d_in[10];
    float* out = (float*)d_out;

    const int* src = ei;
    const int* dst = ei + N_EDGES;

    // carve workspace (256B-aligned)
    char* p = (char*)d_ws;
    auto carve = [&](size_t bytes) { void* r = (void*)p; p += (bytes + 255) & ~(size_t)255; return r; };
    int*    cur       = (int*)   carve(sizeof(int) * (size_t)NBUCK * NSUB * CURSTRIDE);   // 800 KB
    uint32* bbuf      = (uint32*)carve(sizeof(uint32) * (size_t)NBUCK * NSUB * SUBCAP);   // 12.8 MB
    int*    bucketBase= (int*)   carve(sizeof(int) * (NBUCK + 1));
    float*  dinv      = (float*) carve(sizeof(float) * N_NODES);
    int*    offsets   = (int*)   carve(sizeof(int) * (N_NODES + 1));
    int*    col       = (int*)   carve(sizeof(int) * N_EDGES);
    ushort* XW        = (ushort*)carve(sizeof(short) * (size_t)N_NODES * NFEAT);
    ushort* H         = (ushort*)carve(sizeof(short) * (size_t)N_NODES * NFEAT);
    ushort* WT        = (ushort*)carve(sizeof(short) * 3 * NFEAT * NFEAT);
    float*  nodeS     = (float*) carve(sizeof(float) * N_NODES);

    const int edgeBlocks = (N_EDGES + 255) / 256;            // 6250
    const int gemmBlocks = (N_NODES + 63) / 64;              // 1563
    const int aggBlocks  = 50000;                            // 6250 * 8 (node-half per wave)

    hipMemsetAsync(cur, 0, sizeof(int) * (size_t)NBUCK * NSUB * CURSTRIDE, stream);
    hipMemsetAsync(nodeS, 0, sizeof(float) * N_NODES, stream);
    k_scatter<<<edgeBlocks, 256, 0, stream>>>(src, dst, cur, bbuf);
    k_bucketscan<<<1, 256, 0, stream>>>(cur, bucketBase, offsets);
    k_build<<<NBUCK, 256, 0, stream>>>(bbuf, cur, bucketBase, col, offsets, dinv);

    k_castw<<<(3 * NFEAT * NFEAT + 255) / 256, 256, 0, stream>>>(W1, W2, W3, WT);

    // layer 1 (cast fused into GEMM A-load)
    k_gemm_x<<<gemmBlocks, 256, 0, stream>>>(x, WT, XW, N_NODES);
    k_agg_h<<<aggBlocks, 256, 0, stream>>>(XW, col, offsets, dinv, b1, H);
    // layer 2
    k_gemm<<<gemmBlocks, 256, 0, stream>>>(H, WT + NFEAT * NFEAT, XW, N_NODES);
    k_agg_h<<<aggBlocks, 256, 0, stream>>>(XW, col, offsets, dinv, b2, H);
    // layer 3
    k_gemm<<<gemmBlocks, 256, 0, stream>>>(H, WT + 2 * NFEAT * NFEAT, XW, N_NODES);
    k_agg_fc_h<<<aggBlocks, 256, 0, stream>>>(XW, col, offsets, dinv, b3, Wfc, nodeS);

    k_pool<<<N_GRAPHS, 256, 0, stream>>>(nodeS, batch, bfc, out);
}

// Round 8
// 529.567 us; speedup vs baseline: 1.4165x; 1.4165x over previous
//
#include <hip/hip_runtime.h>

#define N_NODES   100000
#define N_EDGES   1600000
#define NFEAT     128
#define N_GRAPHS  1024

// ---- bucketed CSR build ----
#define BSHIFT  6
#define NBUCK   1563                 // ceil(100000 / 64)
#define NSUB    8                    // sub-buckets (XCD-heuristic partition)
#define SUBCAP  256                  // mean 128, +11 sigma headroom
#define CURSTRIDE 16                 // one cursor per 64B line

typedef unsigned int uint32;
typedef unsigned short ushort;
typedef __attribute__((ext_vector_type(8))) short short8;   // 8 bf16 (4 VGPRs)
typedef __attribute__((ext_vector_type(4))) float f32x4;

// fp32 -> bf16 bits, round-to-nearest-even (finite inputs)
__device__ inline ushort f2b(float f) {
    uint32 x = __float_as_uint(f);
    uint32 r = x + 0x7fffu + ((x >> 16) & 1u);
    return (ushort)(r >> 16);
}
__device__ inline float blo(uint32 u) { return __uint_as_float(u << 16); }
__device__ inline float bhi(uint32 u) { return __uint_as_float(u & 0xffff0000u); }

// ---------------- phase 1: scatter edges into (bucket, sub) append regions ----------------
__global__ __launch_bounds__(256) void k_scatter(const int* __restrict__ src, const int* __restrict__ dst,
                                                 int* __restrict__ cur, uint32* __restrict__ bbuf) {
    int e = blockIdx.x * 256 + threadIdx.x;
    int sub = blockIdx.x & (NSUB - 1);
    if (e < N_EDGES) {
        int s = src[e], d = dst[e];
        int b = d >> BSHIFT;
        int slot = (b << 3) | sub;
        int p = atomicAdd(&cur[slot * CURSTRIDE], 1);
        if (p < SUBCAP)
            bbuf[slot * SUBCAP + p] = (uint32)(((d & 63) << 17) | s);
    }
}

// ---------------- exclusive scan of bucket totals -> bucketBase, + offsets[N] ----------------
__global__ __launch_bounds__(256) void k_bucketscan(const int* __restrict__ cur, int* __restrict__ bucketBase,
                                                    int* __restrict__ offsets) {
    __shared__ int wsum[4];
    int t = threadIdx.x;
    int v[7];
    int ts = 0;
    #pragma unroll
    for (int i = 0; i < 7; ++i) {
        int b = t * 7 + i;
        int sz = 0;
        if (b < NBUCK) {
            #pragma unroll
            for (int s = 0; s < NSUB; ++s) {
                int c = cur[((b << 3) | s) * CURSTRIDE];
                sz += (c < SUBCAP) ? c : SUBCAP;
            }
        }
        v[i] = sz;
        ts += sz;
    }
    int lane = t & 63, w = t >> 6;
    int inc = ts;
    #pragma unroll
    for (int d = 1; d < 64; d <<= 1) {
        int u = __shfl_up(inc, d, 64);
        if (lane >= d) inc += u;
    }
    if (lane == 63) wsum[w] = inc;
    __syncthreads();
    int wpre = 0;
    for (int i = 0; i < w; ++i) wpre += wsum[i];
    int run = wpre + inc - ts;
    #pragma unroll
    for (int i = 0; i < 7; ++i) {
        int b = t * 7 + i;
        if (b < NBUCK) bucketBase[b] = run;
        run += v[i];
    }
    if (t == 255) offsets[N_NODES] = run;   // == N_EDGES
}

// ---------------- phase 2: per-bucket local sort -> coalesced CSR + dinv + offsets ----------------
__global__ __launch_bounds__(256) void k_build(const uint32* __restrict__ bbuf, const int* __restrict__ cur,
                                               const int* __restrict__ bucketBase, int* __restrict__ col,
                                               int* __restrict__ offsets, float* __restrict__ dinv) {
    int b = blockIdx.x;
    __shared__ uint32 ebuf[NSUB * SUBCAP];    // 8 KB
    __shared__ int sorted[NSUB * SUBCAP];     // 8 KB
    __shared__ int hist[64], lcur[64];
    __shared__ int subOff[NSUB + 1];
    int t = threadIdx.x;
    if (t == 0) {
        int run = 0;
        #pragma unroll
        for (int s = 0; s < NSUB; ++s) {
            subOff[s] = run;
            int c = cur[((b << 3) | s) * CURSTRIDE];
            run += (c < SUBCAP) ? c : SUBCAP;
        }
        subOff[NSUB] = run;
    }
    if (t < 64) hist[t] = 0;
    __syncthreads();
    int cnt = subOff[NSUB];
    #pragma unroll
    for (int s = 0; s < NSUB; ++s) {
        int n = subOff[s + 1] - subOff[s];
        const uint32* p = bbuf + ((b << 3) | s) * SUBCAP;
        for (int i = t; i < n; i += 256) ebuf[subOff[s] + i] = p[i];
    }
    __syncthreads();
    for (int i = t; i < cnt; i += 256) atomicAdd(&hist[ebuf[i] >> 17], 1);
    __syncthreads();
    int nb = b << BSHIFT;
    if (t < 64) {   // wave 0: scan 64 counts, emit offsets + dinv
        int c = hist[t];
        int inc = c;
        #pragma unroll
        for (int d = 1; d < 64; d <<= 1) {
            int u = __shfl_up(inc, d, 64);
            if (t >= d) inc += u;
        }
        int excl = inc - c;
        lcur[t] = excl;
        int node = nb + t;
        if (node < N_NODES) {
            offsets[node] = bucketBase[b] + excl;
            dinv[node] = rsqrtf((float)(c + 1));
        }
    }
    __syncthreads();
    for (int i = t; i < cnt; i += 256) {
        uint32 p = ebuf[i];
        int lp = atomicAdd(&lcur[p >> 17], 1);
        sorted[lp] = (int)(p & 0x1FFFF);
    }
    __syncthreads();
    int base = bucketBase[b];
    for (int i = t; i < cnt; i += 256) col[base + i] = sorted[i];
}

// ---------------- cast + transpose W1,W2,W3 -> WT bf16 [layer][n][k] ----------------
__global__ __launch_bounds__(256) void k_castw(const float* __restrict__ W1, const float* __restrict__ W2,
                                               const float* __restrict__ W3, ushort* __restrict__ WT) {
    int i = blockIdx.x * blockDim.x + threadIdx.x;   // 3*16384
    if (i >= 3 * NFEAT * NFEAT) return;
    int l = i >> 14;
    int j = i & 16383;
    int n = j >> 7;
    int k = j & 127;
    const float* W = (l == 0) ? W1 : (l == 1) ? W2 : W3;
    WT[i] = f2b(W[k * NFEAT + n]);   // WT[l][n*128+k] = W[k][n]
}

// ---------------- bf16 MFMA GEMM: C[M,128] = A[M,128] @ W ----------------
// Epilogue stages the 64x128 bf16 C-tile in LDS (reusing sWT) -> dwordx4 stores.
#define WT_STRIDE 136
#define GEMM_EPILOGUE \
    __syncthreads(); \
    { \
        ushort* sC = sWT; \
        int colBase = lane & 15; \
        _Pragma("unroll") \
        for (int r = 0; r < 4; ++r) { \
            int lr = wave * 16 + kg * 4 + r; \
            _Pragma("unroll") \
            for (int nt = 0; nt < 8; ++nt) \
                sC[lr * NFEAT + nt * 16 + colBase] = f2b(acc[nt][r]); \
        } \
    } \
    __syncthreads(); \
    { \
        int rowBase = blockIdx.x * 64; \
        const float4* sC4 = (const float4*)sWT; \
        for (int i = t; i < 1024; i += 256) { \
            int row = i >> 4; \
            int gr = rowBase + row; \
            if (gr < M) ((float4*)(C + (size_t)gr * NFEAT))[i & 15] = sC4[i]; \
        } \
    }

__global__ __launch_bounds__(256) void k_gemm(const ushort* __restrict__ A,
                                              const ushort* __restrict__ WTl,
                                              ushort* __restrict__ C, int M) {
    __shared__ ushort sWT[NFEAT * WT_STRIDE];   // 34 KB
    int t = threadIdx.x;
    for (int i = t; i < NFEAT * 16; i += 256) {
        int n = i >> 4, c = i & 15;
        *(float4*)(sWT + n * WT_STRIDE + c * 8) = ((const float4*)WTl)[i];
    }
    int wave = t >> 6, lane = t & 63;
    int m0 = blockIdx.x * 64 + wave * 16;
    int mRow = m0 + (lane & 15);
    if (mRow >= M) mRow = M - 1;
    int kg = lane >> 4;
    const short8* Ap = (const short8*)(A + (size_t)mRow * NFEAT + kg * 8);
    short8 a0 = Ap[0];
    short8 a1 = Ap[4];
    short8 a2 = Ap[8];
    short8 a3 = Ap[12];
    __syncthreads();

    f32x4 acc[8];
    #pragma unroll
    for (int nt = 0; nt < 8; ++nt) acc[nt] = (f32x4){0.f, 0.f, 0.f, 0.f};

    #pragma unroll
    for (int nt = 0; nt < 8; ++nt) {
        int n = nt * 16 + (lane & 15);
        const short8* Bp = (const short8*)(sWT + n * WT_STRIDE + kg * 8);
        short8 b0 = Bp[0];
        short8 b1 = Bp[4];
        short8 b2 = Bp[8];
        short8 b3 = Bp[12];
        acc[nt] = __builtin_amdgcn_mfma_f32_16x16x32_bf16(a0, b0, acc[nt], 0, 0, 0);
        acc[nt] = __builtin_amdgcn_mfma_f32_16x16x32_bf16(a1, b1, acc[nt], 0, 0, 0);
        acc[nt] = __builtin_amdgcn_mfma_f32_16x16x32_bf16(a2, b2, acc[nt], 0, 0, 0);
        acc[nt] = __builtin_amdgcn_mfma_f32_16x16x32_bf16(a3, b3, acc[nt], 0, 0, 0);
    }
    GEMM_EPILOGUE
}

// ---------------- same GEMM but A is fp32 (layer 1: fuses the x->bf16 cast) ----------------
__device__ inline short8 cvt8(const float* p) {
    float4 v0 = ((const float4*)p)[0];
    float4 v1 = ((const float4*)p)[1];
    short8 r;
    r[0] = (short)f2b(v0.x); r[1] = (short)f2b(v0.y);
    r[2] = (short)f2b(v0.z); r[3] = (short)f2b(v0.w);
    r[4] = (short)f2b(v1.x); r[5] = (short)f2b(v1.y);
    r[6] = (short)f2b(v1.z); r[7] = (short)f2b(v1.w);
    return r;
}

__global__ __launch_bounds__(256) void k_gemm_x(const float* __restrict__ A,
                                                const ushort* __restrict__ WTl,
                                                ushort* __restrict__ C, int M) {
    __shared__ ushort sWT[NFEAT * WT_STRIDE];   // 34 KB
    int t = threadIdx.x;
    for (int i = t; i < NFEAT * 16; i += 256) {
        int n = i >> 4, c = i & 15;
        *(float4*)(sWT + n * WT_STRIDE + c * 8) = ((const float4*)WTl)[i];
    }
    int wave = t >> 6, lane = t & 63;
    int m0 = blockIdx.x * 64 + wave * 16;
    int mRow = m0 + (lane & 15);
    if (mRow >= M) mRow = M - 1;
    int kg = lane >> 4;
    const float* Ap = A + (size_t)mRow * NFEAT + kg * 8;
    short8 a0 = cvt8(Ap);
    short8 a1 = cvt8(Ap + 32);
    short8 a2 = cvt8(Ap + 64);
    short8 a3 = cvt8(Ap + 96);
    __syncthreads();

    f32x4 acc[8];
    #pragma unroll
    for (int nt = 0; nt < 8; ++nt) acc[nt] = (f32x4){0.f, 0.f, 0.f, 0.f};

    #pragma unroll
    for (int nt = 0; nt < 8; ++nt) {
        int n = nt * 16 + (lane & 15);
        const short8* Bp = (const short8*)(sWT + n * WT_STRIDE + kg * 8);
        short8 b0 = Bp[0];
        short8 b1 = Bp[4];
        short8 b2 = Bp[8];
        short8 b3 = Bp[12];
        acc[nt] = __builtin_amdgcn_mfma_f32_16x16x32_bf16(a0, b0, acc[nt], 0, 0, 0);
        acc[nt] = __builtin_amdgcn_mfma_f32_16x16x32_bf16(a1, b1, acc[nt], 0, 0, 0);
        acc[nt] = __builtin_amdgcn_mfma_f32_16x16x32_bf16(a2, b2, acc[nt], 0, 0, 0);
        acc[nt] = __builtin_amdgcn_mfma_f32_16x16x32_bf16(a3, b3, acc[nt], 0, 0, 0);
    }
    GEMM_EPILOGUE
}

// ---------------- aggregation core: coalesced metadata + shfl broadcast + NT row gathers ----------------
// XW rows are single-use random -> non-temporal (bypass L1, whose fill path is the ~6 TB/s pin).
// col/dinv keep normal caching (reuse).
#define AGG_BODY \
    float dn = dinv[n]; \
    uint32 v = XWu[(size_t)n * 64 + lane]; \
    float ax = dn * dn * blo(v); \
    float ay = dn * dn * bhi(v); \
    int e0 = off[n], e1 = off[n + 1]; \
    for (int base = e0; base < e1; base += 64) { \
        int len = e1 - base; if (len > 64) len = 64; \
        int cm = (lane < len) ? col[base + lane] : 0; \
        float wm = (lane < len) ? dn * dinv[cm] : 0.f; \
        int j = 0; \
        for (; j + 8 <= len; j += 8) { \
            int cc0 = __shfl(cm, j + 0, 64); int cc1 = __shfl(cm, j + 1, 64); \
            int cc2 = __shfl(cm, j + 2, 64); int cc3 = __shfl(cm, j + 3, 64); \
            int cc4 = __shfl(cm, j + 4, 64); int cc5 = __shfl(cm, j + 5, 64); \
            int cc6 = __shfl(cm, j + 6, 64); int cc7 = __shfl(cm, j + 7, 64); \
            float w0 = __shfl(wm, j + 0, 64); float w1 = __shfl(wm, j + 1, 64); \
            float w2 = __shfl(wm, j + 2, 64); float w3 = __shfl(wm, j + 3, 64); \
            float w4 = __shfl(wm, j + 4, 64); float w5 = __shfl(wm, j + 5, 64); \
            float w6 = __shfl(wm, j + 6, 64); float w7 = __shfl(wm, j + 7, 64); \
            uint32 u0 = __builtin_nontemporal_load(XWu + (size_t)cc0 * 64 + lane); \
            uint32 u1 = __builtin_nontemporal_load(XWu + (size_t)cc1 * 64 + lane); \
            uint32 u2 = __builtin_nontemporal_load(XWu + (size_t)cc2 * 64 + lane); \
            uint32 u3 = __builtin_nontemporal_load(XWu + (size_t)cc3 * 64 + lane); \
            uint32 u4 = __builtin_nontemporal_load(XWu + (size_t)cc4 * 64 + lane); \
            uint32 u5 = __builtin_nontemporal_load(XWu + (size_t)cc5 * 64 + lane); \
            uint32 u6 = __builtin_nontemporal_load(XWu + (size_t)cc6 * 64 + lane); \
            uint32 u7 = __builtin_nontemporal_load(XWu + (size_t)cc7 * 64 + lane); \
            ax = fmaf(w0, blo(u0), ax); ay = fmaf(w0, bhi(u0), ay); \
            ax = fmaf(w1, blo(u1), ax); ay = fmaf(w1, bhi(u1), ay); \
            ax = fmaf(w2, blo(u2), ax); ay = fmaf(w2, bhi(u2), ay); \
            ax = fmaf(w3, blo(u3), ax); ay = fmaf(w3, bhi(u3), ay); \
            ax = fmaf(w4, blo(u4), ax); ay = fmaf(w4, bhi(u4), ay); \
            ax = fmaf(w5, blo(u5), ax); ay = fmaf(w5, bhi(u5), ay); \
            ax = fmaf(w6, blo(u6), ax); ay = fmaf(w6, bhi(u6), ay); \
            ax = fmaf(w7, blo(u7), ax); ay = fmaf(w7, bhi(u7), ay); \
        } \
        for (; j < len; ++j) { \
            int cc = __shfl(cm, j, 64); \
            float ww = __shfl(wm, j, 64); \
            uint32 u = __builtin_nontemporal_load(XWu + (size_t)cc * 64 + lane); \
            ax = fmaf(ww, blo(u), ax); ay = fmaf(ww, bhi(u), ay); \
        } \
    }

__global__ __launch_bounds__(256) void k_agg(const uint32* __restrict__ XWu, const int* __restrict__ col,
                                             const int* __restrict__ off, const float* __restrict__ dinv,
                                             const float* __restrict__ bias, uint32* __restrict__ Hu) {
    int wid = (blockIdx.x * blockDim.x + threadIdx.x) >> 6;
    int lane = threadIdx.x & 63;
    if (wid >= N_NODES) return;
    int n = wid;
    AGG_BODY
    float2 bb = ((const float2*)bias)[lane];
    float ox = fmaxf(ax + bb.x, 0.f);
    float oy = fmaxf(ay + bb.y, 0.f);
    Hu[(size_t)n * 64 + lane] = (uint32)f2b(ox) | ((uint32)f2b(oy) << 16);
}

// ---------------- layer-3 aggregation + relu + FC dot -> per-node scalar ----------------
__global__ __launch_bounds__(256) void k_agg_fc(const uint32* __restrict__ XWu, const int* __restrict__ col,
                                                const int* __restrict__ off, const float* __restrict__ dinv,
                                                const float* __restrict__ bias, const float* __restrict__ Wfc,
                                                float* __restrict__ nodeS) {
    int wid = (blockIdx.x * blockDim.x + threadIdx.x) >> 6;
    int lane = threadIdx.x & 63;
    if (wid >= N_NODES) return;
    int n = wid;
    AGG_BODY
    float2 bb = ((const float2*)bias)[lane];
    float hx = fmaxf(ax + bb.x, 0.f);
    float hy = fmaxf(ay + bb.y, 0.f);
    float2 wf = ((const float2*)Wfc)[lane];
    float s = hx * wf.x + hy * wf.y;
    for (int d = 32; d > 0; d >>= 1) s += __shfl_down(s, d, 64);
    if (lane == 0) nodeS[n] = s;
}

// ---------------- segment mean over sorted batch + bias (one block per graph) ----------------
__device__ inline int lower_bound_dev(const int* a, int n, int key) {
    int lo = 0, hi = n;
    while (lo < hi) {
        int mid = (lo + hi) >> 1;
        if (a[mid] < key) lo = mid + 1; else hi = mid;
    }
    return lo;
}

__global__ __launch_bounds__(256) void k_pool(const float* __restrict__ nodeS, const int* __restrict__ batch,
                                              const float* __restrict__ bfc, float* __restrict__ out) {
    int g = blockIdx.x;
    int t = threadIdx.x;
    int lo = lower_bound_dev(batch, N_NODES, g);
    int hi = lower_bound_dev(batch, N_NODES, g + 1);
    float s = 0.f;
    for (int i = lo + t; i < hi; i += 256) s += nodeS[i];
    for (int d = 32; d > 0; d >>= 1) s += __shfl_down(s, d, 64);
    __shared__ float ws[4];
    int lane = t & 63, w = t >> 6;
    if (lane == 0) ws[w] = s;
    __syncthreads();
    if (t == 0) {
        float tot = ws[0] + ws[1] + ws[2] + ws[3];
        float cnt = (float)(hi - lo);
        out[g] = tot / fmaxf(cnt, 1.0f) + bfc[0];
    }
}

// ---------------- launch ----------------
extern "C" void kernel_launch(void* const* d_in, const int* in_sizes, int n_in,
                              void* d_out, int out_size, void* d_ws, size_t ws_size,
                              hipStream_t stream) {
    const float* x    = (const float*)d_in[0];
    const int*   ei   = (const int*)d_in[1];     // [2, E] : row0 = src, row1 = dst
    const int*   batch= (const int*)d_in[2];
    const float* W1   = (const float*)d_in[3];
    const float* b1   = (const float*)d_in[4];
    const float* W2   = (const float*)d_in[5];
    const float* b2   = (const float*)d_in[6];
    const float* W3   = (const float*)d_in[7];
    const float* b3   = (const float*)d_in[8];
    const float* Wfc  = (const float*)d_in[9];
    const float* bfc  = (const float*)d_in[10];
    float* out = (float*)d_out;

    const int* src = ei;
    const int* dst = ei + N_EDGES;

    // carve workspace (256B-aligned)
    char* p = (char*)d_ws;
    auto carve = [&](size_t bytes) { void* r = (void*)p; p += (bytes + 255) & ~(size_t)255; return r; };
    int*    cur       = (int*)   carve(sizeof(int) * (size_t)NBUCK * NSUB * CURSTRIDE);   // 800 KB
    float*  nodeS     = (float*) carve(sizeof(float) * N_NODES);                           // adjacent: one memset
    uint32* bbuf      = (uint32*)carve(sizeof(uint32) * (size_t)NBUCK * NSUB * SUBCAP);   // 12.8 MB
    int*    bucketBase= (int*)   carve(sizeof(int) * (NBUCK + 1));
    float*  dinv      = (float*) carve(sizeof(float) * N_NODES);
    int*    offsets   = (int*)   carve(sizeof(int) * (N_NODES + 1));
    int*    col       = (int*)   carve(sizeof(int) * N_EDGES);
    ushort* XW        = (ushort*)carve(sizeof(short) * (size_t)N_NODES * NFEAT);
    ushort* H         = (ushort*)carve(sizeof(short) * (size_t)N_NODES * NFEAT);
    ushort* WT        = (ushort*)carve(sizeof(short) * 3 * NFEAT * NFEAT);

    const int edgeBlocks = (N_EDGES + 255) / 256;            // 6250
    const int waveNodeBlocks = (N_NODES * 64 + 255) / 256;   // 25000
    const int gemmBlocks = (N_NODES + 63) / 64;              // 1563

    // cur + nodeS are adjacent: single memset covers both
    size_t zeroBytes = ((sizeof(int) * (size_t)NBUCK * NSUB * CURSTRIDE + 255) & ~(size_t)255)
                     + sizeof(float) * N_NODES;
    hipMemsetAsync(cur, 0, zeroBytes, stream);
    k_scatter<<<edgeBlocks, 256, 0, stream>>>(src, dst, cur, bbuf);
    k_bucketscan<<<1, 256, 0, stream>>>(cur, bucketBase, offsets);
    k_build<<<NBUCK, 256, 0, stream>>>(bbuf, cur, bucketBase, col, offsets, dinv);

    k_castw<<<(3 * NFEAT * NFEAT + 255) / 256, 256, 0, stream>>>(W1, W2, W3, WT);

    // layer 1 (cast fused into GEMM A-load)
    k_gemm_x<<<gemmBlocks, 256, 0, stream>>>(x, WT, XW, N_NODES);
    k_agg<<<waveNodeBlocks, 256, 0, stream>>>((const uint32*)XW, col, offsets, dinv, b1, (uint32*)H);
    // layer 2
    k_gemm<<<gemmBlocks, 256, 0, stream>>>(H, WT + NFEAT * NFEAT, XW, N_NODES);
    k_agg<<<waveNodeBlocks, 256, 0, stream>>>((const uint32*)XW, col, offsets, dinv, b2, (uint32*)H);
    // layer 3
    k_gemm<<<gemmBlocks, 256, 0, stream>>>(H, WT + 2 * NFEAT * NFEAT, XW, N_NODES);
    k_agg_fc<<<waveNodeBlocks, 256, 0, stream>>>((const uint32*)XW, col, offsets, dinv, b3, Wfc, nodeS);

    k_pool<<<N_GRAPHS, 256, 0, stream>>>(nodeS, batch, bfc, out);
}

// Round 9
// 442.558 us; speedup vs baseline: 1.6949x; 1.1966x over previous
//
#include <hip/hip_runtime.h>

#define N_NODES   100000
#define N_EDGES   1600000
#define NFEAT     128
#define N_GRAPHS  1024

// ---- bucketed CSR build ----
#define BSHIFT  6
#define NBUCK   1563                 // ceil(100000 / 64)
#define NSUB    8                    // sub-buckets (XCD-heuristic partition)
#define SUBCAP  256                  // mean 128, +11 sigma headroom
#define CURSTRIDE 16                 // one cursor per 64B line

typedef unsigned int uint32;
typedef unsigned short ushort;
typedef __attribute__((ext_vector_type(8))) short short8;   // 8 bf16 (4 VGPRs)
typedef __attribute__((ext_vector_type(4))) float f32x4;

// fp32 -> bf16 bits, round-to-nearest-even (finite inputs)
__device__ inline ushort f2b(float f) {
    uint32 x = __float_as_uint(f);
    uint32 r = x + 0x7fffu + ((x >> 16) & 1u);
    return (ushort)(r >> 16);
}
__device__ inline float blo(uint32 u) { return __uint_as_float(u << 16); }
__device__ inline float bhi(uint32 u) { return __uint_as_float(u & 0xffff0000u); }

// ---------------- phase 1: scatter edges into (bucket, sub) append regions ----------------
__global__ __launch_bounds__(256) void k_scatter(const int* __restrict__ src, const int* __restrict__ dst,
                                                 int* __restrict__ cur, uint32* __restrict__ bbuf) {
    int e = blockIdx.x * 256 + threadIdx.x;
    int sub = blockIdx.x & (NSUB - 1);
    if (e < N_EDGES) {
        int s = src[e], d = dst[e];
        int b = d >> BSHIFT;
        int slot = (b << 3) | sub;
        int p = atomicAdd(&cur[slot * CURSTRIDE], 1);
        if (p < SUBCAP)
            bbuf[slot * SUBCAP + p] = (uint32)(((d & 63) << 17) | s);
    }
}

// ---------------- exclusive scan of bucket totals -> bucketBase, + offsets[N] ----------------
__global__ __launch_bounds__(256) void k_bucketscan(const int* __restrict__ cur, int* __restrict__ bucketBase,
                                                    int* __restrict__ offsets) {
    __shared__ int wsum[4];
    int t = threadIdx.x;
    int v[7];
    int ts = 0;
    #pragma unroll
    for (int i = 0; i < 7; ++i) {
        int b = t * 7 + i;
        int sz = 0;
        if (b < NBUCK) {
            #pragma unroll
            for (int s = 0; s < NSUB; ++s) {
                int c = cur[((b << 3) | s) * CURSTRIDE];
                sz += (c < SUBCAP) ? c : SUBCAP;
            }
        }
        v[i] = sz;
        ts += sz;
    }
    int lane = t & 63, w = t >> 6;
    int inc = ts;
    #pragma unroll
    for (int d = 1; d < 64; d <<= 1) {
        int u = __shfl_up(inc, d, 64);
        if (lane >= d) inc += u;
    }
    if (lane == 63) wsum[w] = inc;
    __syncthreads();
    int wpre = 0;
    for (int i = 0; i < w; ++i) wpre += wsum[i];
    int run = wpre + inc - ts;
    #pragma unroll
    for (int i = 0; i < 7; ++i) {
        int b = t * 7 + i;
        if (b < NBUCK) bucketBase[b] = run;
        run += v[i];
    }
    if (t == 255) offsets[N_NODES] = run;   // == N_EDGES
}

// ---------------- phase 2: per-bucket local sort -> coalesced CSR + dinv + offsets ----------------
__global__ __launch_bounds__(256) void k_build(const uint32* __restrict__ bbuf, const int* __restrict__ cur,
                                               const int* __restrict__ bucketBase, int* __restrict__ col,
                                               int* __restrict__ offsets, float* __restrict__ dinv) {
    int b = blockIdx.x;
    __shared__ uint32 ebuf[NSUB * SUBCAP];    // 8 KB
    __shared__ int sorted[NSUB * SUBCAP];     // 8 KB
    __shared__ int hist[64], lcur[64];
    __shared__ int subOff[NSUB + 1];
    int t = threadIdx.x;
    if (t == 0) {
        int run = 0;
        #pragma unroll
        for (int s = 0; s < NSUB; ++s) {
            subOff[s] = run;
            int c = cur[((b << 3) | s) * CURSTRIDE];
            run += (c < SUBCAP) ? c : SUBCAP;
        }
        subOff[NSUB] = run;
    }
    if (t < 64) hist[t] = 0;
    __syncthreads();
    int cnt = subOff[NSUB];
    #pragma unroll
    for (int s = 0; s < NSUB; ++s) {
        int n = subOff[s + 1] - subOff[s];
        const uint32* p = bbuf + ((b << 3) | s) * SUBCAP;
        for (int i = t; i < n; i += 256) ebuf[subOff[s] + i] = p[i];
    }
    __syncthreads();
    for (int i = t; i < cnt; i += 256) atomicAdd(&hist[ebuf[i] >> 17], 1);
    __syncthreads();
    int nb = b << BSHIFT;
    if (t < 64) {   // wave 0: scan 64 counts, emit offsets + dinv
        int c = hist[t];
        int inc = c;
        #pragma unroll
        for (int d = 1; d < 64; d <<= 1) {
            int u = __shfl_up(inc, d, 64);
            if (t >= d) inc += u;
        }
        int excl = inc - c;
        lcur[t] = excl;
        int node = nb + t;
        if (node < N_NODES) {
            offsets[node] = bucketBase[b] + excl;
            dinv[node] = rsqrtf((float)(c + 1));
        }
    }
    __syncthreads();
    for (int i = t; i < cnt; i += 256) {
        uint32 p = ebuf[i];
        int lp = atomicAdd(&lcur[p >> 17], 1);
        sorted[lp] = (int)(p & 0x1FFFF);
    }
    __syncthreads();
    int base = bucketBase[b];
    for (int i = t; i < cnt; i += 256) col[base + i] = sorted[i];
}

// ---------------- cast + transpose W1,W2,W3 -> WT bf16 [layer][n][k] ----------------
__global__ __launch_bounds__(256) void k_castw(const float* __restrict__ W1, const float* __restrict__ W2,
                                               const float* __restrict__ W3, ushort* __restrict__ WT) {
    int i = blockIdx.x * blockDim.x + threadIdx.x;   // 3*16384
    if (i >= 3 * NFEAT * NFEAT) return;
    int l = i >> 14;
    int j = i & 16383;
    int n = j >> 7;
    int k = j & 127;
    const float* W = (l == 0) ? W1 : (l == 1) ? W2 : W3;
    WT[i] = f2b(W[k * NFEAT + n]);   // WT[l][n*128+k] = W[k][n]
}

// ---------------- bf16 MFMA GEMM: C[M,128] = A[M,128] @ W ----------------
// Epilogue stages the 64x128 bf16 C-tile in LDS (reusing sWT) -> dwordx4 stores.
#define WT_STRIDE 136
#define GEMM_EPILOGUE \
    __syncthreads(); \
    { \
        ushort* sC = sWT; \
        int colBase = lane & 15; \
        _Pragma("unroll") \
        for (int r = 0; r < 4; ++r) { \
            int lr = wave * 16 + kg * 4 + r; \
            _Pragma("unroll") \
            for (int nt = 0; nt < 8; ++nt) \
                sC[lr * NFEAT + nt * 16 + colBase] = f2b(acc[nt][r]); \
        } \
    } \
    __syncthreads(); \
    { \
        int rowBase = blockIdx.x * 64; \
        const float4* sC4 = (const float4*)sWT; \
        for (int i = t; i < 1024; i += 256) { \
            int row = i >> 4; \
            int gr = rowBase + row; \
            if (gr < M) ((float4*)(C + (size_t)gr * NFEAT))[i & 15] = sC4[i]; \
        } \
    }

__global__ __launch_bounds__(256) void k_gemm(const ushort* __restrict__ A,
                                              const ushort* __restrict__ WTl,
                                              ushort* __restrict__ C, int M) {
    __shared__ ushort sWT[NFEAT * WT_STRIDE];   // 34 KB
    int t = threadIdx.x;
    for (int i = t; i < NFEAT * 16; i += 256) {
        int n = i >> 4, c = i & 15;
        *(float4*)(sWT + n * WT_STRIDE + c * 8) = ((const float4*)WTl)[i];
    }
    int wave = t >> 6, lane = t & 63;
    int m0 = blockIdx.x * 64 + wave * 16;
    int mRow = m0 + (lane & 15);
    if (mRow >= M) mRow = M - 1;
    int kg = lane >> 4;
    const short8* Ap = (const short8*)(A + (size_t)mRow * NFEAT + kg * 8);
    short8 a0 = Ap[0];
    short8 a1 = Ap[4];
    short8 a2 = Ap[8];
    short8 a3 = Ap[12];
    __syncthreads();

    f32x4 acc[8];
    #pragma unroll
    for (int nt = 0; nt < 8; ++nt) acc[nt] = (f32x4){0.f, 0.f, 0.f, 0.f};

    #pragma unroll
    for (int nt = 0; nt < 8; ++nt) {
        int n = nt * 16 + (lane & 15);
        const short8* Bp = (const short8*)(sWT + n * WT_STRIDE + kg * 8);
        short8 b0 = Bp[0];
        short8 b1 = Bp[4];
        short8 b2 = Bp[8];
        short8 b3 = Bp[12];
        acc[nt] = __builtin_amdgcn_mfma_f32_16x16x32_bf16(a0, b0, acc[nt], 0, 0, 0);
        acc[nt] = __builtin_amdgcn_mfma_f32_16x16x32_bf16(a1, b1, acc[nt], 0, 0, 0);
        acc[nt] = __builtin_amdgcn_mfma_f32_16x16x32_bf16(a2, b2, acc[nt], 0, 0, 0);
        acc[nt] = __builtin_amdgcn_mfma_f32_16x16x32_bf16(a3, b3, acc[nt], 0, 0, 0);
    }
    GEMM_EPILOGUE
}

// ---------------- same GEMM but A is fp32 (layer 1: fuses the x->bf16 cast) ----------------
__device__ inline short8 cvt8(const float* p) {
    float4 v0 = ((const float4*)p)[0];
    float4 v1 = ((const float4*)p)[1];
    short8 r;
    r[0] = (short)f2b(v0.x); r[1] = (short)f2b(v0.y);
    r[2] = (short)f2b(v0.z); r[3] = (short)f2b(v0.w);
    r[4] = (short)f2b(v1.x); r[5] = (short)f2b(v1.y);
    r[6] = (short)f2b(v1.z); r[7] = (short)f2b(v1.w);
    return r;
}

__global__ __launch_bounds__(256) void k_gemm_x(const float* __restrict__ A,
                                                const ushort* __restrict__ WTl,
                                                ushort* __restrict__ C, int M) {
    __shared__ ushort sWT[NFEAT * WT_STRIDE];   // 34 KB
    int t = threadIdx.x;
    for (int i = t; i < NFEAT * 16; i += 256) {
        int n = i >> 4, c = i & 15;
        *(float4*)(sWT + n * WT_STRIDE + c * 8) = ((const float4*)WTl)[i];
    }
    int wave = t >> 6, lane = t & 63;
    int m0 = blockIdx.x * 64 + wave * 16;
    int mRow = m0 + (lane & 15);
    if (mRow >= M) mRow = M - 1;
    int kg = lane >> 4;
    const float* Ap = A + (size_t)mRow * NFEAT + kg * 8;
    short8 a0 = cvt8(Ap);
    short8 a1 = cvt8(Ap + 32);
    short8 a2 = cvt8(Ap + 64);
    short8 a3 = cvt8(Ap + 96);
    __syncthreads();

    f32x4 acc[8];
    #pragma unroll
    for (int nt = 0; nt < 8; ++nt) acc[nt] = (f32x4){0.f, 0.f, 0.f, 0.f};

    #pragma unroll
    for (int nt = 0; nt < 8; ++nt) {
        int n = nt * 16 + (lane & 15);
        const short8* Bp = (const short8*)(sWT + n * WT_STRIDE + kg * 8);
        short8 b0 = Bp[0];
        short8 b1 = Bp[4];
        short8 b2 = Bp[8];
        short8 b3 = Bp[12];
        acc[nt] = __builtin_amdgcn_mfma_f32_16x16x32_bf16(a0, b0, acc[nt], 0, 0, 0);
        acc[nt] = __builtin_amdgcn_mfma_f32_16x16x32_bf16(a1, b1, acc[nt], 0, 0, 0);
        acc[nt] = __builtin_amdgcn_mfma_f32_16x16x32_bf16(a2, b2, acc[nt], 0, 0, 0);
        acc[nt] = __builtin_amdgcn_mfma_f32_16x16x32_bf16(a3, b3, acc[nt], 0, 0, 0);
    }
    GEMM_EPILOGUE
}

// ---------------- aggregation core: shfl-broadcast metadata, 16-deep gather pipeline ----------------
// Plain (cached) loads: each XW row is re-read by ~16 dst nodes, L1/L2 reuse is real.
#define AGG_BODY \
    float dn = dinv[n]; \
    uint32 v = XWu[(size_t)n * 64 + lane]; \
    float ax = dn * dn * blo(v); \
    float ay = dn * dn * bhi(v); \
    int e0 = off[n], e1 = off[n + 1]; \
    for (int base = e0; base < e1; base += 64) { \
        int len = e1 - base; if (len > 64) len = 64; \
        int cm = (lane < len) ? col[base + lane] : 0; \
        float wm = (lane < len) ? dn * dinv[cm] : 0.f; \
        int j = 0; \
        for (; j + 16 <= len; j += 16) { \
            uint32 u[16]; \
            float w[16]; \
            _Pragma("unroll") \
            for (int i = 0; i < 16; ++i) { \
                int cc = __shfl(cm, j + i, 64); \
                w[i] = __shfl(wm, j + i, 64); \
                u[i] = XWu[(size_t)cc * 64 + lane]; \
            } \
            _Pragma("unroll") \
            for (int i = 0; i < 16; ++i) { \
                ax = fmaf(w[i], blo(u[i]), ax); \
                ay = fmaf(w[i], bhi(u[i]), ay); \
            } \
        } \
        for (; j + 4 <= len; j += 4) { \
            uint32 u[4]; \
            float w[4]; \
            _Pragma("unroll") \
            for (int i = 0; i < 4; ++i) { \
                int cc = __shfl(cm, j + i, 64); \
                w[i] = __shfl(wm, j + i, 64); \
                u[i] = XWu[(size_t)cc * 64 + lane]; \
            } \
            _Pragma("unroll") \
            for (int i = 0; i < 4; ++i) { \
                ax = fmaf(w[i], blo(u[i]), ax); \
                ay = fmaf(w[i], bhi(u[i]), ay); \
            } \
        } \
        for (; j < len; ++j) { \
            int cc = __shfl(cm, j, 64); \
            float ww = __shfl(wm, j, 64); \
            uint32 u = XWu[(size_t)cc * 64 + lane]; \
            ax = fmaf(ww, blo(u), ax); ay = fmaf(ww, bhi(u), ay); \
        } \
    }

__global__ __launch_bounds__(256) void k_agg(const uint32* __restrict__ XWu, const int* __restrict__ col,
                                             const int* __restrict__ off, const float* __restrict__ dinv,
                                             const float* __restrict__ bias, uint32* __restrict__ Hu) {
    int wid = (blockIdx.x * blockDim.x + threadIdx.x) >> 6;
    int lane = threadIdx.x & 63;
    if (wid >= N_NODES) return;
    int n = wid;
    AGG_BODY
    float2 bb = ((const float2*)bias)[lane];
    float ox = fmaxf(ax + bb.x, 0.f);
    float oy = fmaxf(ay + bb.y, 0.f);
    Hu[(size_t)n * 64 + lane] = (uint32)f2b(ox) | ((uint32)f2b(oy) << 16);
}

// ---------------- layer-3 aggregation + relu + FC dot -> per-node scalar ----------------
__global__ __launch_bounds__(256) void k_agg_fc(const uint32* __restrict__ XWu, const int* __restrict__ col,
                                                const int* __restrict__ off, const float* __restrict__ dinv,
                                                const float* __restrict__ bias, const float* __restrict__ Wfc,
                                                float* __restrict__ nodeS) {
    int wid = (blockIdx.x * blockDim.x + threadIdx.x) >> 6;
    int lane = threadIdx.x & 63;
    if (wid >= N_NODES) return;
    int n = wid;
    AGG_BODY
    float2 bb = ((const float2*)bias)[lane];
    float hx = fmaxf(ax + bb.x, 0.f);
    float hy = fmaxf(ay + bb.y, 0.f);
    float2 wf = ((const float2*)Wfc)[lane];
    float s = hx * wf.x + hy * wf.y;
    for (int d = 32; d > 0; d >>= 1) s += __shfl_down(s, d, 64);
    if (lane == 0) nodeS[n] = s;
}

// ---------------- segment mean over sorted batch + bias (one block per graph) ----------------
__device__ inline int lower_bound_dev(const int* a, int n, int key) {
    int lo = 0, hi = n;
    while (lo < hi) {
        int mid = (lo + hi) >> 1;
        if (a[mid] < key) lo = mid + 1; else hi = mid;
    }
    return lo;
}

__global__ __launch_bounds__(256) void k_pool(const float* __restrict__ nodeS, const int* __restrict__ batch,
                                              const float* __restrict__ bfc, float* __restrict__ out) {
    int g = blockIdx.x;
    int t = threadIdx.x;
    int lo = lower_bound_dev(batch, N_NODES, g);
    int hi = lower_bound_dev(batch, N_NODES, g + 1);
    float s = 0.f;
    for (int i = lo + t; i < hi; i += 256) s += nodeS[i];
    for (int d = 32; d > 0; d >>= 1) s += __shfl_down(s, d, 64);
    __shared__ float ws[4];
    int lane = t & 63, w = t >> 6;
    if (lane == 0) ws[w] = s;
    __syncthreads();
    if (t == 0) {
        float tot = ws[0] + ws[1] + ws[2] + ws[3];
        float cnt = (float)(hi - lo);
        out[g] = tot / fmaxf(cnt, 1.0f) + bfc[0];
    }
}

// ---------------- launch ----------------
extern "C" void kernel_launch(void* const* d_in, const int* in_sizes, int n_in,
                              void* d_out, int out_size, void* d_ws, size_t ws_size,
                              hipStream_t stream) {
    const float* x    = (const float*)d_in[0];
    const int*   ei   = (const int*)d_in[1];     // [2, E] : row0 = src, row1 = dst
    const int*   batch= (const int*)d_in[2];
    const float* W1   = (const float*)d_in[3];
    const float* b1   = (const float*)d_in[4];
    const float* W2   = (const float*)d_in[5];
    const float* b2   = (const float*)d_in[6];
    const float* W3   = (const float*)d_in[7];
    const float* b3   = (const float*)d_in[8];
    const float* Wfc  = (const float*)d_in[9];
    const float* bfc  = (const float*)d_in[10];
    float* out = (float*)d_out;

    const int* src = ei;
    const int* dst = ei + N_EDGES;

    // carve workspace (256B-aligned)
    char* p = (char*)d_ws;
    auto carve = [&](size_t bytes) { void* r = (void*)p; p += (bytes + 255) & ~(size_t)255; return r; };
    int*    cur       = (int*)   carve(sizeof(int) * (size_t)NBUCK * NSUB * CURSTRIDE);   // 800 KB
    float*  nodeS     = (float*) carve(sizeof(float) * N_NODES);                           // adjacent: one memset
    uint32* bbuf      = (uint32*)carve(sizeof(uint32) * (size_t)NBUCK * NSUB * SUBCAP);   // 12.8 MB
    int*    bucketBase= (int*)   carve(sizeof(int) * (NBUCK + 1));
    float*  dinv      = (float*) carve(sizeof(float) * N_NODES);
    int*    offsets   = (int*)   carve(sizeof(int) * (N_NODES + 1));
    int*    col       = (int*)   carve(sizeof(int) * N_EDGES);
    ushort* XW        = (ushort*)carve(sizeof(short) * (size_t)N_NODES * NFEAT);
    ushort* H         = (ushort*)carve(sizeof(short) * (size_t)N_NODES * NFEAT);
    ushort* WT        = (ushort*)carve(sizeof(short) * 3 * NFEAT * NFEAT);

    const int edgeBlocks = (N_EDGES + 255) / 256;            // 6250
    const int waveNodeBlocks = (N_NODES * 64 + 255) / 256;   // 25000
    const int gemmBlocks = (N_NODES + 63) / 64;              // 1563

    // cur + nodeS are adjacent: single memset covers both
    size_t zeroBytes = ((sizeof(int) * (size_t)NBUCK * NSUB * CURSTRIDE + 255) & ~(size_t)255)
                     + sizeof(float) * N_NODES;
    hipMemsetAsync(cur, 0, zeroBytes, stream);
    k_scatter<<<edgeBlocks, 256, 0, stream>>>(src, dst, cur, bbuf);
    k_bucketscan<<<1, 256, 0, stream>>>(cur, bucketBase, offsets);
    k_build<<<NBUCK, 256, 0, stream>>>(bbuf, cur, bucketBase, col, offsets, dinv);

    k_castw<<<(3 * NFEAT * NFEAT + 255) / 256, 256, 0, stream>>>(W1, W2, W3, WT);

    // layer 1 (cast fused into GEMM A-load)
    k_gemm_x<<<gemmBlocks, 256, 0, stream>>>(x, WT, XW, N_NODES);
    k_agg<<<waveNodeBlocks, 256, 0, stream>>>((const uint32*)XW, col, offsets, dinv, b1, (uint32*)H);
    // layer 2
    k_gemm<<<gemmBlocks, 256, 0, stream>>>(H, WT + NFEAT * NFEAT, XW, N_NODES);
    k_agg<<<waveNodeBlocks, 256, 0, stream>>>((const uint32*)XW, col, offsets, dinv, b2, (uint32*)H);
    // layer 3
    k_gemm<<<gemmBlocks, 256, 0, stream>>>(H, WT + 2 * NFEAT * NFEAT, XW, N_NODES);
    k_agg_fc<<<waveNodeBlocks, 256, 0, stream>>>((const uint32*)XW, col, offsets, dinv, b3, Wfc, nodeS);

    k_pool<<<N_GRAPHS, 256, 0, stream>>>(nodeS, batch, bfc, out);
}

// Round 10
// 433.606 us; speedup vs baseline: 1.7299x; 1.0206x over previous
//
#include <hip/hip_runtime.h>

#define N_NODES   100000
#define N_EDGES   1600000
#define NFEAT     128
#define N_GRAPHS  1024

// ---- bucketed CSR build ----
#define BSHIFT  6
#define NBUCK   1563                 // ceil(100000 / 64)
#define NSUB    8                    // sub-buckets (XCD-heuristic partition)
#define SUBCAP  256                  // mean 128, +11 sigma headroom
#define CURSTRIDE 16                 // one cursor per 64B line

typedef unsigned int uint32;
typedef unsigned short ushort;
typedef __attribute__((ext_vector_type(8))) short short8;   // 8 bf16 (4 VGPRs)
typedef __attribute__((ext_vector_type(4))) float f32x4;

// fp32 -> bf16 bits, round-to-nearest-even (finite inputs)
__device__ inline ushort f2b(float f) {
    uint32 x = __float_as_uint(f);
    uint32 r = x + 0x7fffu + ((x >> 16) & 1u);
    return (ushort)(r >> 16);
}
__device__ inline float blo(uint32 u) { return __uint_as_float(u << 16); }
__device__ inline float bhi(uint32 u) { return __uint_as_float(u & 0xffff0000u); }

// ---------------- phase 1: scatter edges into (bucket, sub) append regions ----------------
__global__ __launch_bounds__(256) void k_scatter(const int* __restrict__ src, const int* __restrict__ dst,
                                                 int* __restrict__ cur, uint32* __restrict__ bbuf) {
    int e = blockIdx.x * 256 + threadIdx.x;
    int sub = blockIdx.x & (NSUB - 1);
    if (e < N_EDGES) {
        int s = src[e], d = dst[e];
        int b = d >> BSHIFT;
        int slot = (b << 3) | sub;
        int p = atomicAdd(&cur[slot * CURSTRIDE], 1);
        if (p < SUBCAP)
            bbuf[slot * SUBCAP + p] = (uint32)(((d & 63) << 17) | s);
    }
}

// ---------------- exclusive scan of bucket totals -> bucketBase, + offsets[N] ----------------
__global__ __launch_bounds__(256) void k_bucketscan(const int* __restrict__ cur, int* __restrict__ bucketBase,
                                                    int* __restrict__ offsets) {
    __shared__ int wsum[4];
    int t = threadIdx.x;
    int v[7];
    int ts = 0;
    #pragma unroll
    for (int i = 0; i < 7; ++i) {
        int b = t * 7 + i;
        int sz = 0;
        if (b < NBUCK) {
            #pragma unroll
            for (int s = 0; s < NSUB; ++s) {
                int c = cur[((b << 3) | s) * CURSTRIDE];
                sz += (c < SUBCAP) ? c : SUBCAP;
            }
        }
        v[i] = sz;
        ts += sz;
    }
    int lane = t & 63, w = t >> 6;
    int inc = ts;
    #pragma unroll
    for (int d = 1; d < 64; d <<= 1) {
        int u = __shfl_up(inc, d, 64);
        if (lane >= d) inc += u;
    }
    if (lane == 63) wsum[w] = inc;
    __syncthreads();
    int wpre = 0;
    for (int i = 0; i < w; ++i) wpre += wsum[i];
    int run = wpre + inc - ts;
    #pragma unroll
    for (int i = 0; i < 7; ++i) {
        int b = t * 7 + i;
        if (b < NBUCK) bucketBase[b] = run;
        run += v[i];
    }
    if (t == 255) offsets[N_NODES] = run;   // == N_EDGES
}

// ---------------- phase 2: per-bucket local sort -> coalesced CSR + dinv + offsets ----------------
__global__ __launch_bounds__(256) void k_build(const uint32* __restrict__ bbuf, const int* __restrict__ cur,
                                               const int* __restrict__ bucketBase, int* __restrict__ col,
                                               int* __restrict__ offsets, float* __restrict__ dinv) {
    int b = blockIdx.x;
    __shared__ uint32 ebuf[NSUB * SUBCAP];    // 8 KB
    __shared__ int sorted[NSUB * SUBCAP];     // 8 KB
    __shared__ int hist[64], lcur[64];
    __shared__ int subOff[NSUB + 1];
    int t = threadIdx.x;
    if (t == 0) {
        int run = 0;
        #pragma unroll
        for (int s = 0; s < NSUB; ++s) {
            subOff[s] = run;
            int c = cur[((b << 3) | s) * CURSTRIDE];
            run += (c < SUBCAP) ? c : SUBCAP;
        }
        subOff[NSUB] = run;
    }
    if (t < 64) hist[t] = 0;
    __syncthreads();
    int cnt = subOff[NSUB];
    #pragma unroll
    for (int s = 0; s < NSUB; ++s) {
        int n = subOff[s + 1] - subOff[s];
        const uint32* p = bbuf + ((b << 3) | s) * SUBCAP;
        for (int i = t; i < n; i += 256) ebuf[subOff[s] + i] = p[i];
    }
    __syncthreads();
    for (int i = t; i < cnt; i += 256) atomicAdd(&hist[ebuf[i] >> 17], 1);
    __syncthreads();
    int nb = b << BSHIFT;
    if (t < 64) {   // wave 0: scan 64 counts, emit offsets + dinv
        int c = hist[t];
        int inc = c;
        #pragma unroll
        for (int d = 1; d < 64; d <<= 1) {
            int u = __shfl_up(inc, d, 64);
            if (t >= d) inc += u;
        }
        int excl = inc - c;
        lcur[t] = excl;
        int node = nb + t;
        if (node < N_NODES) {
            offsets[node] = bucketBase[b] + excl;
            dinv[node] = rsqrtf((float)(c + 1));
        }
    }
    __syncthreads();
    for (int i = t; i < cnt; i += 256) {
        uint32 p = ebuf[i];
        int lp = atomicAdd(&lcur[p >> 17], 1);
        sorted[lp] = (int)(p & 0x1FFFF);
    }
    __syncthreads();
    int base = bucketBase[b];
    for (int i = t; i < cnt; i += 256) col[base + i] = sorted[i];
}

// ---------------- cast + transpose W1,W2,W3 -> WT bf16 [layer][n][k] ----------------
__global__ __launch_bounds__(256) void k_castw(const float* __restrict__ W1, const float* __restrict__ W2,
                                               const float* __restrict__ W3, ushort* __restrict__ WT) {
    int i = blockIdx.x * blockDim.x + threadIdx.x;   // 3*16384
    if (i >= 3 * NFEAT * NFEAT) return;
    int l = i >> 14;
    int j = i & 16383;
    int n = j >> 7;
    int k = j & 127;
    const float* W = (l == 0) ? W1 : (l == 1) ? W2 : W3;
    WT[i] = f2b(W[k * NFEAT + n]);   // WT[l][n*128+k] = W[k][n]
}

// ---------------- bf16 MFMA GEMM: C[M,128] = A[M,128] @ W ----------------
// Epilogue stages the 64x128 bf16 C-tile in LDS (reusing sWT) -> dwordx4 stores.
#define WT_STRIDE 136
#define GEMM_EPILOGUE \
    __syncthreads(); \
    { \
        ushort* sC = sWT; \
        int colBase = lane & 15; \
        _Pragma("unroll") \
        for (int r = 0; r < 4; ++r) { \
            int lr = wave * 16 + kg * 4 + r; \
            _Pragma("unroll") \
            for (int nt = 0; nt < 8; ++nt) \
                sC[lr * NFEAT + nt * 16 + colBase] = f2b(acc[nt][r]); \
        } \
    } \
    __syncthreads(); \
    { \
        int rowBase = blockIdx.x * 64; \
        const float4* sC4 = (const float4*)sWT; \
        for (int i = t; i < 1024; i += 256) { \
            int row = i >> 4; \
            int gr = rowBase + row; \
            if (gr < M) ((float4*)(C + (size_t)gr * NFEAT))[i & 15] = sC4[i]; \
        } \
    }

__global__ __launch_bounds__(256) void k_gemm(const ushort* __restrict__ A,
                                              const ushort* __restrict__ WTl,
                                              ushort* __restrict__ C, int M) {
    __shared__ ushort sWT[NFEAT * WT_STRIDE];   // 34 KB
    int t = threadIdx.x;
    for (int i = t; i < NFEAT * 16; i += 256) {
        int n = i >> 4, c = i & 15;
        *(float4*)(sWT + n * WT_STRIDE + c * 8) = ((const float4*)WTl)[i];
    }
    int wave = t >> 6, lane = t & 63;
    int m0 = blockIdx.x * 64 + wave * 16;
    int mRow = m0 + (lane & 15);
    if (mRow >= M) mRow = M - 1;
    int kg = lane >> 4;
    const short8* Ap = (const short8*)(A + (size_t)mRow * NFEAT + kg * 8);
    short8 a0 = Ap[0];
    short8 a1 = Ap[4];
    short8 a2 = Ap[8];
    short8 a3 = Ap[12];
    __syncthreads();

    f32x4 acc[8];
    #pragma unroll
    for (int nt = 0; nt < 8; ++nt) acc[nt] = (f32x4){0.f, 0.f, 0.f, 0.f};

    #pragma unroll
    for (int nt = 0; nt < 8; ++nt) {
        int n = nt * 16 + (lane & 15);
        const short8* Bp = (const short8*)(sWT + n * WT_STRIDE + kg * 8);
        short8 b0 = Bp[0];
        short8 b1 = Bp[4];
        short8 b2 = Bp[8];
        short8 b3 = Bp[12];
        acc[nt] = __builtin_amdgcn_mfma_f32_16x16x32_bf16(a0, b0, acc[nt], 0, 0, 0);
        acc[nt] = __builtin_amdgcn_mfma_f32_16x16x32_bf16(a1, b1, acc[nt], 0, 0, 0);
        acc[nt] = __builtin_amdgcn_mfma_f32_16x16x32_bf16(a2, b2, acc[nt], 0, 0, 0);
        acc[nt] = __builtin_amdgcn_mfma_f32_16x16x32_bf16(a3, b3, acc[nt], 0, 0, 0);
    }
    GEMM_EPILOGUE
}

// ---------------- same GEMM but A is fp32 (layer 1: fuses the x->bf16 cast) ----------------
__device__ inline short8 cvt8(const float* p) {
    float4 v0 = ((const float4*)p)[0];
    float4 v1 = ((const float4*)p)[1];
    short8 r;
    r[0] = (short)f2b(v0.x); r[1] = (short)f2b(v0.y);
    r[2] = (short)f2b(v0.z); r[3] = (short)f2b(v0.w);
    r[4] = (short)f2b(v1.x); r[5] = (short)f2b(v1.y);
    r[6] = (short)f2b(v1.z); r[7] = (short)f2b(v1.w);
    return r;
}

__global__ __launch_bounds__(256) void k_gemm_x(const float* __restrict__ A,
                                                const ushort* __restrict__ WTl,
                                                ushort* __restrict__ C, int M) {
    __shared__ ushort sWT[NFEAT * WT_STRIDE];   // 34 KB
    int t = threadIdx.x;
    for (int i = t; i < NFEAT * 16; i += 256) {
        int n = i >> 4, c = i & 15;
        *(float4*)(sWT + n * WT_STRIDE + c * 8) = ((const float4*)WTl)[i];
    }
    int wave = t >> 6, lane = t & 63;
    int m0 = blockIdx.x * 64 + wave * 16;
    int mRow = m0 + (lane & 15);
    if (mRow >= M) mRow = M - 1;
    int kg = lane >> 4;
    const float* Ap = A + (size_t)mRow * NFEAT + kg * 8;
    short8 a0 = cvt8(Ap);
    short8 a1 = cvt8(Ap + 32);
    short8 a2 = cvt8(Ap + 64);
    short8 a3 = cvt8(Ap + 96);
    __syncthreads();

    f32x4 acc[8];
    #pragma unroll
    for (int nt = 0; nt < 8; ++nt) acc[nt] = (f32x4){0.f, 0.f, 0.f, 0.f};

    #pragma unroll
    for (int nt = 0; nt < 8; ++nt) {
        int n = nt * 16 + (lane & 15);
        const short8* Bp = (const short8*)(sWT + n * WT_STRIDE + kg * 8);
        short8 b0 = Bp[0];
        short8 b1 = Bp[4];
        short8 b2 = Bp[8];
        short8 b3 = Bp[12];
        acc[nt] = __builtin_amdgcn_mfma_f32_16x16x32_bf16(a0, b0, acc[nt], 0, 0, 0);
        acc[nt] = __builtin_amdgcn_mfma_f32_16x16x32_bf16(a1, b1, acc[nt], 0, 0, 0);
        acc[nt] = __builtin_amdgcn_mfma_f32_16x16x32_bf16(a2, b2, acc[nt], 0, 0, 0);
        acc[nt] = __builtin_amdgcn_mfma_f32_16x16x32_bf16(a3, b3, acc[nt], 0, 0, 0);
    }
    GEMM_EPILOGUE
}

// ---------------- aggregation core v3: 4 edges per uint4 gather instruction ----------------
// half = lane>>4 picks edge j+half; fl = lane&15 picks feature octet 8fl..8fl+7.
// One wave-wide dwordx4 load fetches 4 edges' rows -> 1/4 the VMEM instructions
// and 1/4 the per-edge address-divergence cost. Accs combined via shfl_xor(32,16).
#define AGG_BODY4 \
    float dn = dinv[n]; \
    int half = lane >> 4; \
    int fl = lane & 15; \
    const uint4* XW4 = (const uint4*)XWu; \
    uint4 sv = XW4[(size_t)n * 16 + fl]; \
    float ws = (half == 0) ? dn * dn : 0.f; \
    float a0 = ws * blo(sv.x), a1 = ws * bhi(sv.x); \
    float a2 = ws * blo(sv.y), a3 = ws * bhi(sv.y); \
    float a4 = ws * blo(sv.z), a5 = ws * bhi(sv.z); \
    float a6 = ws * blo(sv.w), a7 = ws * bhi(sv.w); \
    int e0 = off[n], e1 = off[n + 1]; \
    for (int base = e0; base < e1; base += 64) { \
        int len = e1 - base; if (len > 64) len = 64; \
        int cm = (lane < len) ? col[base + lane] : 0; \
        float wm = (lane < len) ? dn * dinv[cm] : 0.f; \
        int j = 0; \
        for (; j + 16 <= len; j += 16) { \
            uint4 u[4]; float w[4]; \
            _Pragma("unroll") \
            for (int p = 0; p < 4; ++p) { \
                int idx = j + 4 * p + half; \
                int cc = __shfl(cm, idx, 64); \
                w[p] = __shfl(wm, idx, 64); \
                u[p] = XW4[(size_t)cc * 16 + fl]; \
            } \
            _Pragma("unroll") \
            for (int p = 0; p < 4; ++p) { \
                a0 = fmaf(w[p], blo(u[p].x), a0); a1 = fmaf(w[p], bhi(u[p].x), a1); \
                a2 = fmaf(w[p], blo(u[p].y), a2); a3 = fmaf(w[p], bhi(u[p].y), a3); \
                a4 = fmaf(w[p], blo(u[p].z), a4); a5 = fmaf(w[p], bhi(u[p].z), a5); \
                a6 = fmaf(w[p], blo(u[p].w), a6); a7 = fmaf(w[p], bhi(u[p].w), a7); \
            } \
        } \
        for (; j < len; j += 4) { \
            int rem = len - j; \
            int idx = j + ((half < rem) ? half : 0); \
            int cc = __shfl(cm, idx, 64); \
            float ww = __shfl(wm, idx, 64); \
            if (half >= rem) ww = 0.f; \
            uint4 u = XW4[(size_t)cc * 16 + fl]; \
            a0 = fmaf(ww, blo(u.x), a0); a1 = fmaf(ww, bhi(u.x), a1); \
            a2 = fmaf(ww, blo(u.y), a2); a3 = fmaf(ww, bhi(u.y), a3); \
            a4 = fmaf(ww, blo(u.z), a4); a5 = fmaf(ww, bhi(u.z), a5); \
            a6 = fmaf(ww, blo(u.w), a6); a7 = fmaf(ww, bhi(u.w), a7); \
        } \
    } \
    a0 += __shfl_xor(a0, 32, 64); a0 += __shfl_xor(a0, 16, 64); \
    a1 += __shfl_xor(a1, 32, 64); a1 += __shfl_xor(a1, 16, 64); \
    a2 += __shfl_xor(a2, 32, 64); a2 += __shfl_xor(a2, 16, 64); \
    a3 += __shfl_xor(a3, 32, 64); a3 += __shfl_xor(a3, 16, 64); \
    a4 += __shfl_xor(a4, 32, 64); a4 += __shfl_xor(a4, 16, 64); \
    a5 += __shfl_xor(a5, 32, 64); a5 += __shfl_xor(a5, 16, 64); \
    a6 += __shfl_xor(a6, 32, 64); a6 += __shfl_xor(a6, 16, 64); \
    a7 += __shfl_xor(a7, 32, 64); a7 += __shfl_xor(a7, 16, 64);

__global__ __launch_bounds__(256) void k_agg(const uint32* __restrict__ XWu, const int* __restrict__ col,
                                             const int* __restrict__ off, const float* __restrict__ dinv,
                                             const float* __restrict__ bias, uint32* __restrict__ Hu) {
    int wid = (blockIdx.x * blockDim.x + threadIdx.x) >> 6;
    int lane = threadIdx.x & 63;
    if (wid >= N_NODES) return;
    int n = wid;
    AGG_BODY4
    if (half == 0) {
        float4 bb0 = ((const float4*)bias)[2 * fl];
        float4 bb1 = ((const float4*)bias)[2 * fl + 1];
        float r0 = fmaxf(a0 + bb0.x, 0.f), r1 = fmaxf(a1 + bb0.y, 0.f);
        float r2 = fmaxf(a2 + bb0.z, 0.f), r3 = fmaxf(a3 + bb0.w, 0.f);
        float r4 = fmaxf(a4 + bb1.x, 0.f), r5 = fmaxf(a5 + bb1.y, 0.f);
        float r6 = fmaxf(a6 + bb1.z, 0.f), r7 = fmaxf(a7 + bb1.w, 0.f);
        uint4 o;
        o.x = (uint32)f2b(r0) | ((uint32)f2b(r1) << 16);
        o.y = (uint32)f2b(r2) | ((uint32)f2b(r3) << 16);
        o.z = (uint32)f2b(r4) | ((uint32)f2b(r5) << 16);
        o.w = (uint32)f2b(r6) | ((uint32)f2b(r7) << 16);
        ((uint4*)Hu)[(size_t)n * 16 + fl] = o;
    }
}

// ---------------- layer-3 aggregation + relu + FC dot -> per-node scalar ----------------
__global__ __launch_bounds__(256) void k_agg_fc(const uint32* __restrict__ XWu, const int* __restrict__ col,
                                                const int* __restrict__ off, const float* __restrict__ dinv,
                                                const float* __restrict__ bias, const float* __restrict__ Wfc,
                                                float* __restrict__ nodeS) {
    int wid = (blockIdx.x * blockDim.x + threadIdx.x) >> 6;
    int lane = threadIdx.x & 63;
    if (wid >= N_NODES) return;
    int n = wid;
    AGG_BODY4
    float4 bb0 = ((const float4*)bias)[2 * fl];
    float4 bb1 = ((const float4*)bias)[2 * fl + 1];
    float4 wf0 = ((const float4*)Wfc)[2 * fl];
    float4 wf1 = ((const float4*)Wfc)[2 * fl + 1];
    float s = fmaxf(a0 + bb0.x, 0.f) * wf0.x + fmaxf(a1 + bb0.y, 0.f) * wf0.y
            + fmaxf(a2 + bb0.z, 0.f) * wf0.z + fmaxf(a3 + bb0.w, 0.f) * wf0.w
            + fmaxf(a4 + bb1.x, 0.f) * wf1.x + fmaxf(a5 + bb1.y, 0.f) * wf1.y
            + fmaxf(a6 + bb1.z, 0.f) * wf1.z + fmaxf(a7 + bb1.w, 0.f) * wf1.w;
    s += __shfl_xor(s, 8, 64);
    s += __shfl_xor(s, 4, 64);
    s += __shfl_xor(s, 2, 64);
    s += __shfl_xor(s, 1, 64);
    if (lane == 0) nodeS[n] = s;
}

// ---------------- segment mean over sorted batch + bias (one block per graph) ----------------
__device__ inline int lower_bound_dev(const int* a, int n, int key) {
    int lo = 0, hi = n;
    while (lo < hi) {
        int mid = (lo + hi) >> 1;
        if (a[mid] < key) lo = mid + 1; else hi = mid;
    }
    return lo;
}

__global__ __launch_bounds__(256) void k_pool(const float* __restrict__ nodeS, const int* __restrict__ batch,
                                              const float* __restrict__ bfc, float* __restrict__ out) {
    int g = blockIdx.x;
    int t = threadIdx.x;
    int lo = lower_bound_dev(batch, N_NODES, g);
    int hi = lower_bound_dev(batch, N_NODES, g + 1);
    float s = 0.f;
    for (int i = lo + t; i < hi; i += 256) s += nodeS[i];
    for (int d = 32; d > 0; d >>= 1) s += __shfl_down(s, d, 64);
    __shared__ float ws[4];
    int lane = t & 63, w = t >> 6;
    if (lane == 0) ws[w] = s;
    __syncthreads();
    if (t == 0) {
        float tot = ws[0] + ws[1] + ws[2] + ws[3];
        float cnt = (float)(hi - lo);
        out[g] = tot / fmaxf(cnt, 1.0f) + bfc[0];
    }
}

// ---------------- launch ----------------
extern "C" void kernel_launch(void* const* d_in, const int* in_sizes, int n_in,
                              void* d_out, int out_size, void* d_ws, size_t ws_size,
                              hipStream_t stream) {
    const float* x    = (const float*)d_in[0];
    const int*   ei   = (const int*)d_in[1];     // [2, E] : row0 = src, row1 = dst
    const int*   batch= (const int*)d_in[2];
    const float* W1   = (const float*)d_in[3];
    const float* b1   = (const float*)d_in[4];
    const float* W2   = (const float*)d_in[5];
    const float* b2   = (const float*)d_in[6];
    const float* W3   = (const float*)d_in[7];
    const float* b3   = (const float*)d_in[8];
    const float* Wfc  = (const float*)d_in[9];
    const float* bfc  = (const float*)d_in[10];
    float* out = (float*)d_out;

    const int* src = ei;
    const int* dst = ei + N_EDGES;

    // carve workspace (256B-aligned)
    char* p = (char*)d_ws;
    auto carve = [&](size_t bytes) { void* r = (void*)p; p += (bytes + 255) & ~(size_t)255; return r; };
    int*    cur       = (int*)   carve(sizeof(int) * (size_t)NBUCK * NSUB * CURSTRIDE);   // 800 KB
    uint32* bbuf      = (uint32*)carve(sizeof(uint32) * (size_t)NBUCK * NSUB * SUBCAP);   // 12.8 MB
    int*    bucketBase= (int*)   carve(sizeof(int) * (NBUCK + 1));
    float*  dinv      = (float*) carve(sizeof(float) * N_NODES);
    int*    offsets   = (int*)   carve(sizeof(int) * (N_NODES + 1));
    int*    col       = (int*)   carve(sizeof(int) * N_EDGES);
    ushort* XW        = (ushort*)carve(sizeof(short) * (size_t)N_NODES * NFEAT);
    ushort* H         = (ushort*)carve(sizeof(short) * (size_t)N_NODES * NFEAT);
    ushort* WT        = (ushort*)carve(sizeof(short) * 3 * NFEAT * NFEAT);
    float*  nodeS     = (float*) carve(sizeof(float) * N_NODES);

    const int edgeBlocks = (N_EDGES + 255) / 256;            // 6250
    const int waveNodeBlocks = (N_NODES * 64 + 255) / 256;   // 25000
    const int gemmBlocks = (N_NODES + 63) / 64;              // 1563

    hipMemsetAsync(cur, 0, sizeof(int) * (size_t)NBUCK * NSUB * CURSTRIDE, stream);
    k_scatter<<<edgeBlocks, 256, 0, stream>>>(src, dst, cur, bbuf);
    k_bucketscan<<<1, 256, 0, stream>>>(cur, bucketBase, offsets);
    k_build<<<NBUCK, 256, 0, stream>>>(bbuf, cur, bucketBase, col, offsets, dinv);

    k_castw<<<(3 * NFEAT * NFEAT + 255) / 256, 256, 0, stream>>>(W1, W2, W3, WT);

    // layer 1 (cast fused into GEMM A-load)
    k_gemm_x<<<gemmBlocks, 256, 0, stream>>>(x, WT, XW, N_NODES);
    k_agg<<<waveNodeBlocks, 256, 0, stream>>>((const uint32*)XW, col, offsets, dinv, b1, (uint32*)H);
    // layer 2
    k_gemm<<<gemmBlocks, 256, 0, stream>>>(H, WT + NFEAT * NFEAT, XW, N_NODES);
    k_agg<<<waveNodeBlocks, 256, 0, stream>>>((const uint32*)XW, col, offsets, dinv, b2, (uint32*)H);
    // layer 3
    k_gemm<<<gemmBlocks, 256, 0, stream>>>(H, WT + 2 * NFEAT * NFEAT, XW, N_NODES);
    k_agg_fc<<<waveNodeBlocks, 256, 0, stream>>>((const uint32*)XW, col, offsets, dinv, b3, Wfc, nodeS);

    k_pool<<<N_GRAPHS, 256, 0, stream>>>(nodeS, batch, bfc, out);
}

// Round 11
// 393.208 us; speedup vs baseline: 1.9077x; 1.1027x over previous
//
#include <hip/hip_runtime.h>

#define N_NODES   100000
#define N_EDGES   1600000
#define NFEAT     128
#define N_GRAPHS  1024

// ---- bucketed CSR build (256-node buckets, block-local counting-sort scatter) ----
#define BSHIFT  8
#define BNODES  256
#define NBUCK   391                  // ceil(100000 / 256)
#define BCAP    4608                 // mean 4096 + 8 sigma
#define SC_EDGES 8192
#define SC_BLOCKS 196                // ceil(1.6M / 8192)

typedef unsigned int uint32;
typedef unsigned short ushort;
typedef __attribute__((ext_vector_type(8))) short short8;   // 8 bf16 (4 VGPRs)
typedef __attribute__((ext_vector_type(4))) float f32x4;

// fp32 -> bf16 bits, round-to-nearest-even (finite inputs)
__device__ inline ushort f2b(float f) {
    uint32 x = __float_as_uint(f);
    uint32 r = x + 0x7fffu + ((x >> 16) & 1u);
    return (ushort)(r >> 16);
}
__device__ inline float blo(uint32 u) { return __uint_as_float(u << 16); }
__device__ inline float bhi(uint32 u) { return __uint_as_float(u & 0xffff0000u); }

// ---------------- scatter: block-local counting sort -> burst writes, 1 atomic per (block,bin) ----------------
__global__ __launch_bounds__(256) void k_scatter(const int* __restrict__ src, const int* __restrict__ dst,
                                                 int* __restrict__ cur, uint32* __restrict__ bbuf) {
    __shared__ int hist[NBUCK];
    __shared__ int lofs[NBUCK];
    __shared__ int lcur[NBUCK];
    __shared__ int gbase[NBUCK];
    __shared__ int wsum[4];
    __shared__ uint32 sortedP[SC_EDGES];   // 32 KB
    __shared__ ushort sortedB[SC_EDGES];   // 16 KB
    int t = threadIdx.x;
    int e0 = blockIdx.x * SC_EDGES;
    int total = N_EDGES - e0; if (total > SC_EDGES) total = SC_EDGES; if (total < 0) total = 0;

    for (int i = t; i < NBUCK; i += 256) hist[i] = 0;
    __syncthreads();
    // pass 1: histogram over dst buckets
    for (int i = t; i < total; i += 256)
        atomicAdd(&hist[dst[e0 + i] >> BSHIFT], 1);
    __syncthreads();
    // block-scan of 391 bins (2 bins/thread) + per-bin global reservation
    {
        int b0 = 2 * t, b1 = 2 * t + 1;
        int h0 = (b0 < NBUCK) ? hist[b0] : 0;
        int h1 = (b1 < NBUCK) ? hist[b1] : 0;
        int ts = h0 + h1;
        int lane = t & 63, w = t >> 6;
        int inc = ts;
        #pragma unroll
        for (int d = 1; d < 64; d <<= 1) {
            int u = __shfl_up(inc, d, 64);
            if (lane >= d) inc += u;
        }
        if (lane == 63) wsum[w] = inc;
        __syncthreads();
        int wpre = 0;
        for (int i = 0; i < w; ++i) wpre += wsum[i];
        int run = wpre + inc - ts;
        if (b0 < NBUCK) {
            lofs[b0] = run; lcur[b0] = run;
            if (h0) gbase[b0] = atomicAdd(&cur[b0], h0);
        }
        if (b1 < NBUCK) {
            lofs[b1] = run + h0; lcur[b1] = run + h0;
            if (h1) gbase[b1] = atomicAdd(&cur[b1], h1);
        }
    }
    __syncthreads();
    // pass 2: place edges into LDS, sorted by bucket
    for (int i = t; i < total; i += 256) {
        int s = src[e0 + i], d = dst[e0 + i];
        int b = d >> BSHIFT;
        int p = atomicAdd(&lcur[b], 1);
        sortedP[p] = ((uint32)(d & (BNODES - 1)) << 17) | (uint32)s;
        sortedB[p] = (ushort)b;
    }
    __syncthreads();
    // write out: consecutive threads -> consecutive positions within bucket runs
    for (int i = t; i < total; i += 256) {
        int b = sortedB[i];
        int addr = gbase[b] + (i - lofs[b]);
        if (addr < BCAP)
            bbuf[(size_t)b * BCAP + addr] = sortedP[i];
    }
}

// ---------------- exclusive scan of bucket totals -> bucketBase + offsets[N] ----------------
__global__ __launch_bounds__(256) void k_bucketscan(const int* __restrict__ cur, int* __restrict__ bucketBase,
                                                    int* __restrict__ offsets) {
    __shared__ int wsum[4];
    int t = threadIdx.x;
    int b0 = 2 * t, b1 = 2 * t + 1;
    int h0 = 0, h1 = 0;
    if (b0 < NBUCK) { h0 = cur[b0]; if (h0 > BCAP) h0 = BCAP; }
    if (b1 < NBUCK) { h1 = cur[b1]; if (h1 > BCAP) h1 = BCAP; }
    int ts = h0 + h1;
    int lane = t & 63, w = t >> 6;
    int inc = ts;
    #pragma unroll
    for (int d = 1; d < 64; d <<= 1) {
        int u = __shfl_up(inc, d, 64);
        if (lane >= d) inc += u;
    }
    if (lane == 63) wsum[w] = inc;
    __syncthreads();
    int wpre = 0;
    for (int i = 0; i < w; ++i) wpre += wsum[i];
    int run = wpre + inc - ts;
    if (b0 < NBUCK) bucketBase[b0] = run;
    if (b1 < NBUCK) bucketBase[b1] = run + h0;
    if (t == 255) offsets[N_NODES] = run + ts;   // == total stored edges
}

// ---------------- per-bucket counting sort -> CSR col + offsets + dinv ----------------
__global__ __launch_bounds__(256) void k_build(const uint32* __restrict__ bbuf, const int* __restrict__ cur,
                                               const int* __restrict__ bucketBase, int* __restrict__ col,
                                               int* __restrict__ offsets, float* __restrict__ dinv) {
    int b = blockIdx.x;
    __shared__ int hist[BNODES], lcur[BNODES];
    __shared__ int wsum[4];
    __shared__ int sorted[BCAP];              // 18 KB
    int t = threadIdx.x;
    int cnt = cur[b]; if (cnt > BCAP) cnt = BCAP;
    const uint32* reg = bbuf + (size_t)b * BCAP;
    hist[t] = 0;
    __syncthreads();
    for (int i = t; i < cnt; i += 256) atomicAdd(&hist[reg[i] >> 17], 1);
    __syncthreads();
    // block scan of 256 node-counts
    {
        int c = hist[t];
        int lane = t & 63, w = t >> 6;
        int inc = c;
        #pragma unroll
        for (int d = 1; d < 64; d <<= 1) {
            int u = __shfl_up(inc, d, 64);
            if (lane >= d) inc += u;
        }
        if (lane == 63) wsum[w] = inc;
        __syncthreads();
        int wpre = 0;
        for (int i = 0; i < w; ++i) wpre += wsum[i];
        int excl = wpre + inc - c;
        lcur[t] = excl;
        int node = (b << BSHIFT) + t;
        if (node < N_NODES) {
            offsets[node] = bucketBase[b] + excl;
            dinv[node] = rsqrtf((float)(c + 1));
        }
    }
    __syncthreads();
    for (int i = t; i < cnt; i += 256) {
        uint32 p = reg[i];
        int lp = atomicAdd(&lcur[p >> 17], 1);
        sorted[lp] = (int)(p & 0x1FFFF);
    }
    __syncthreads();
    int base = bucketBase[b];
    for (int i = t; i < cnt; i += 256) col[base + i] = sorted[i];
}

// ---------------- cast + transpose W1,W2,W3 -> WT bf16 [layer][n][k] ----------------
__global__ __launch_bounds__(256) void k_castw(const float* __restrict__ W1, const float* __restrict__ W2,
                                               const float* __restrict__ W3, ushort* __restrict__ WT) {
    int i = blockIdx.x * blockDim.x + threadIdx.x;   // 3*16384
    if (i >= 3 * NFEAT * NFEAT) return;
    int l = i >> 14;
    int j = i & 16383;
    int n = j >> 7;
    int k = j & 127;
    const float* W = (l == 0) ? W1 : (l == 1) ? W2 : W3;
    WT[i] = f2b(W[k * NFEAT + n]);   // WT[l][n*128+k] = W[k][n]
}

// ---------------- bf16 MFMA GEMM: C[M,128] = A[M,128] @ W ----------------
// Epilogue stages the 64x128 bf16 C-tile in LDS (reusing sWT) -> dwordx4 stores.
#define WT_STRIDE 136
#define GEMM_EPILOGUE \
    __syncthreads(); \
    { \
        ushort* sC = sWT; \
        int colBase = lane & 15; \
        _Pragma("unroll") \
        for (int r = 0; r < 4; ++r) { \
            int lr = wave * 16 + kg * 4 + r; \
            _Pragma("unroll") \
            for (int nt = 0; nt < 8; ++nt) \
                sC[lr * NFEAT + nt * 16 + colBase] = f2b(acc[nt][r]); \
        } \
    } \
    __syncthreads(); \
    { \
        int rowBase = blockIdx.x * 64; \
        const float4* sC4 = (const float4*)sWT; \
        for (int i = t; i < 1024; i += 256) { \
            int row = i >> 4; \
            int gr = rowBase + row; \
            if (gr < M) ((float4*)(C + (size_t)gr * NFEAT))[i & 15] = sC4[i]; \
        } \
    }

__global__ __launch_bounds__(256) void k_gemm(const ushort* __restrict__ A,
                                              const ushort* __restrict__ WTl,
                                              ushort* __restrict__ C, int M) {
    __shared__ ushort sWT[NFEAT * WT_STRIDE];   // 34 KB
    int t = threadIdx.x;
    for (int i = t; i < NFEAT * 16; i += 256) {
        int n = i >> 4, c = i & 15;
        *(float4*)(sWT + n * WT_STRIDE + c * 8) = ((const float4*)WTl)[i];
    }
    int wave = t >> 6, lane = t & 63;
    int m0 = blockIdx.x * 64 + wave * 16;
    int mRow = m0 + (lane & 15);
    if (mRow >= M) mRow = M - 1;
    int kg = lane >> 4;
    const short8* Ap = (const short8*)(A + (size_t)mRow * NFEAT + kg * 8);
    short8 a0 = Ap[0];
    short8 a1 = Ap[4];
    short8 a2 = Ap[8];
    short8 a3 = Ap[12];
    __syncthreads();

    f32x4 acc[8];
    #pragma unroll
    for (int nt = 0; nt < 8; ++nt) acc[nt] = (f32x4){0.f, 0.f, 0.f, 0.f};

    #pragma unroll
    for (int nt = 0; nt < 8; ++nt) {
        int n = nt * 16 + (lane & 15);
        const short8* Bp = (const short8*)(sWT + n * WT_STRIDE + kg * 8);
        short8 b0 = Bp[0];
        short8 b1 = Bp[4];
        short8 b2 = Bp[8];
        short8 b3 = Bp[12];
        acc[nt] = __builtin_amdgcn_mfma_f32_16x16x32_bf16(a0, b0, acc[nt], 0, 0, 0);
        acc[nt] = __builtin_amdgcn_mfma_f32_16x16x32_bf16(a1, b1, acc[nt], 0, 0, 0);
        acc[nt] = __builtin_amdgcn_mfma_f32_16x16x32_bf16(a2, b2, acc[nt], 0, 0, 0);
        acc[nt] = __builtin_amdgcn_mfma_f32_16x16x32_bf16(a3, b3, acc[nt], 0, 0, 0);
    }
    GEMM_EPILOGUE
}

// ---------------- same GEMM but A is fp32 (layer 1: fuses the x->bf16 cast) ----------------
__device__ inline short8 cvt8(const float* p) {
    float4 v0 = ((const float4*)p)[0];
    float4 v1 = ((const float4*)p)[1];
    short8 r;
    r[0] = (short)f2b(v0.x); r[1] = (short)f2b(v0.y);
    r[2] = (short)f2b(v0.z); r[3] = (short)f2b(v0.w);
    r[4] = (short)f2b(v1.x); r[5] = (short)f2b(v1.y);
    r[6] = (short)f2b(v1.z); r[7] = (short)f2b(v1.w);
    return r;
}

__global__ __launch_bounds__(256) void k_gemm_x(const float* __restrict__ A,
                                                const ushort* __restrict__ WTl,
                                                ushort* __restrict__ C, int M) {
    __shared__ ushort sWT[NFEAT * WT_STRIDE];   // 34 KB
    int t = threadIdx.x;
    for (int i = t; i < NFEAT * 16; i += 256) {
        int n = i >> 4, c = i & 15;
        *(float4*)(sWT + n * WT_STRIDE + c * 8) = ((const float4*)WTl)[i];
    }
    int wave = t >> 6, lane = t & 63;
    int m0 = blockIdx.x * 64 + wave * 16;
    int mRow = m0 + (lane & 15);
    if (mRow >= M) mRow = M - 1;
    int kg = lane >> 4;
    const float* Ap = A + (size_t)mRow * NFEAT + kg * 8;
    short8 a0 = cvt8(Ap);
    short8 a1 = cvt8(Ap + 32);
    short8 a2 = cvt8(Ap + 64);
    short8 a3 = cvt8(Ap + 96);
    __syncthreads();

    f32x4 acc[8];
    #pragma unroll
    for (int nt = 0; nt < 8; ++nt) acc[nt] = (f32x4){0.f, 0.f, 0.f, 0.f};

    #pragma unroll
    for (int nt = 0; nt < 8; ++nt) {
        int n = nt * 16 + (lane & 15);
        const short8* Bp = (const short8*)(sWT + n * WT_STRIDE + kg * 8);
        short8 b0 = Bp[0];
        short8 b1 = Bp[4];
        short8 b2 = Bp[8];
        short8 b3 = Bp[12];
        acc[nt] = __builtin_amdgcn_mfma_f32_16x16x32_bf16(a0, b0, acc[nt], 0, 0, 0);
        acc[nt] = __builtin_amdgcn_mfma_f32_16x16x32_bf16(a1, b1, acc[nt], 0, 0, 0);
        acc[nt] = __builtin_amdgcn_mfma_f32_16x16x32_bf16(a2, b2, acc[nt], 0, 0, 0);
        acc[nt] = __builtin_amdgcn_mfma_f32_16x16x32_bf16(a3, b3, acc[nt], 0, 0, 0);
    }
    GEMM_EPILOGUE
}

// ---------------- aggregation core: 4 edges per uint4 gather instruction ----------------
#define AGG_BODY4 \
    float dn = dinv[n]; \
    int half = lane >> 4; \
    int fl = lane & 15; \
    const uint4* XW4 = (const uint4*)XWu; \
    uint4 sv = XW4[(size_t)n * 16 + fl]; \
    float ws = (half == 0) ? dn * dn : 0.f; \
    float a0 = ws * blo(sv.x), a1 = ws * bhi(sv.x); \
    float a2 = ws * blo(sv.y), a3 = ws * bhi(sv.y); \
    float a4 = ws * blo(sv.z), a5 = ws * bhi(sv.z); \
    float a6 = ws * blo(sv.w), a7 = ws * bhi(sv.w); \
    int e0 = off[n], e1 = off[n + 1]; \
    for (int base = e0; base < e1; base += 64) { \
        int len = e1 - base; if (len > 64) len = 64; \
        int cm = (lane < len) ? col[base + lane] : 0; \
        float wm = (lane < len) ? dn * dinv[cm] : 0.f; \
        int j = 0; \
        for (; j + 16 <= len; j += 16) { \
            uint4 u[4]; float w[4]; \
            _Pragma("unroll") \
            for (int p = 0; p < 4; ++p) { \
                int idx = j + 4 * p + half; \
                int cc = __shfl(cm, idx, 64); \
                w[p] = __shfl(wm, idx, 64); \
                u[p] = XW4[(size_t)cc * 16 + fl]; \
            } \
            _Pragma("unroll") \
            for (int p = 0; p < 4; ++p) { \
                a0 = fmaf(w[p], blo(u[p].x), a0); a1 = fmaf(w[p], bhi(u[p].x), a1); \
                a2 = fmaf(w[p], blo(u[p].y), a2); a3 = fmaf(w[p], bhi(u[p].y), a3); \
                a4 = fmaf(w[p], blo(u[p].z), a4); a5 = fmaf(w[p], bhi(u[p].z), a5); \
                a6 = fmaf(w[p], blo(u[p].w), a6); a7 = fmaf(w[p], bhi(u[p].w), a7); \
            } \
        } \
        for (; j < len; j += 4) { \
            int rem = len - j; \
            int idx = j + ((half < rem) ? half : 0); \
            int cc = __shfl(cm, idx, 64); \
            float ww = __shfl(wm, idx, 64); \
            if (half >= rem) ww = 0.f; \
            uint4 u = XW4[(size_t)cc * 16 + fl]; \
            a0 = fmaf(ww, blo(u.x), a0); a1 = fmaf(ww, bhi(u.x), a1); \
            a2 = fmaf(ww, blo(u.y), a2); a3 = fmaf(ww, bhi(u.y), a3); \
            a4 = fmaf(ww, blo(u.z), a4); a5 = fmaf(ww, bhi(u.z), a5); \
            a6 = fmaf(ww, blo(u.w), a6); a7 = fmaf(ww, bhi(u.w), a7); \
        } \
    } \
    a0 += __shfl_xor(a0, 32, 64); a0 += __shfl_xor(a0, 16, 64); \
    a1 += __shfl_xor(a1, 32, 64); a1 += __shfl_xor(a1, 16, 64); \
    a2 += __shfl_xor(a2, 32, 64); a2 += __shfl_xor(a2, 16, 64); \
    a3 += __shfl_xor(a3, 32, 64); a3 += __shfl_xor(a3, 16, 64); \
    a4 += __shfl_xor(a4, 32, 64); a4 += __shfl_xor(a4, 16, 64); \
    a5 += __shfl_xor(a5, 32, 64); a5 += __shfl_xor(a5, 16, 64); \
    a6 += __shfl_xor(a6, 32, 64); a6 += __shfl_xor(a6, 16, 64); \
    a7 += __shfl_xor(a7, 32, 64); a7 += __shfl_xor(a7, 16, 64);

__global__ __launch_bounds__(256) void k_agg(const uint32* __restrict__ XWu, const int* __restrict__ col,
                                             const int* __restrict__ off, const float* __restrict__ dinv,
                                             const float* __restrict__ bias, uint32* __restrict__ Hu) {
    int wid = (blockIdx.x * blockDim.x + threadIdx.x) >> 6;
    int lane = threadIdx.x & 63;
    if (wid >= N_NODES) return;
    int n = wid;
    AGG_BODY4
    if (half == 0) {
        float4 bb0 = ((const float4*)bias)[2 * fl];
        float4 bb1 = ((const float4*)bias)[2 * fl + 1];
        float r0 = fmaxf(a0 + bb0.x, 0.f), r1 = fmaxf(a1 + bb0.y, 0.f);
        float r2 = fmaxf(a2 + bb0.z, 0.f), r3 = fmaxf(a3 + bb0.w, 0.f);
        float r4 = fmaxf(a4 + bb1.x, 0.f), r5 = fmaxf(a5 + bb1.y, 0.f);
        float r6 = fmaxf(a6 + bb1.z, 0.f), r7 = fmaxf(a7 + bb1.w, 0.f);
        uint4 o;
        o.x = (uint32)f2b(r0) | ((uint32)f2b(r1) << 16);
        o.y = (uint32)f2b(r2) | ((uint32)f2b(r3) << 16);
        o.z = (uint32)f2b(r4) | ((uint32)f2b(r5) << 16);
        o.w = (uint32)f2b(r6) | ((uint32)f2b(r7) << 16);
        ((uint4*)Hu)[(size_t)n * 16 + fl] = o;
    }
}

// ---------------- layer-3 aggregation + relu + FC dot -> per-node scalar ----------------
__global__ __launch_bounds__(256) void k_agg_fc(const uint32* __restrict__ XWu, const int* __restrict__ col,
                                                const int* __restrict__ off, const float* __restrict__ dinv,
                                                const float* __restrict__ bias, const float* __restrict__ Wfc,
                                                float* __restrict__ nodeS) {
    int wid = (blockIdx.x * blockDim.x + threadIdx.x) >> 6;
    int lane = threadIdx.x & 63;
    if (wid >= N_NODES) return;
    int n = wid;
    AGG_BODY4
    float4 bb0 = ((const float4*)bias)[2 * fl];
    float4 bb1 = ((const float4*)bias)[2 * fl + 1];
    float4 wf0 = ((const float4*)Wfc)[2 * fl];
    float4 wf1 = ((const float4*)Wfc)[2 * fl + 1];
    float s = fmaxf(a0 + bb0.x, 0.f) * wf0.x + fmaxf(a1 + bb0.y, 0.f) * wf0.y
            + fmaxf(a2 + bb0.z, 0.f) * wf0.z + fmaxf(a3 + bb0.w, 0.f) * wf0.w
            + fmaxf(a4 + bb1.x, 0.f) * wf1.x + fmaxf(a5 + bb1.y, 0.f) * wf1.y
            + fmaxf(a6 + bb1.z, 0.f) * wf1.z + fmaxf(a7 + bb1.w, 0.f) * wf1.w;
    s += __shfl_xor(s, 8, 64);
    s += __shfl_xor(s, 4, 64);
    s += __shfl_xor(s, 2, 64);
    s += __shfl_xor(s, 1, 64);
    if (lane == 0) nodeS[n] = s;
}

// ---------------- segment mean over sorted batch + bias (one block per graph) ----------------
__device__ inline int lower_bound_dev(const int* a, int n, int key) {
    int lo = 0, hi = n;
    while (lo < hi) {
        int mid = (lo + hi) >> 1;
        if (a[mid] < key) lo = mid + 1; else hi = mid;
    }
    return lo;
}

__global__ __launch_bounds__(256) void k_pool(const float* __restrict__ nodeS, const int* __restrict__ batch,
                                              const float* __restrict__ bfc, float* __restrict__ out) {
    int g = blockIdx.x;
    int t = threadIdx.x;
    int lo = lower_bound_dev(batch, N_NODES, g);
    int hi = lower_bound_dev(batch, N_NODES, g + 1);
    float s = 0.f;
    for (int i = lo + t; i < hi; i += 256) s += nodeS[i];
    for (int d = 32; d > 0; d >>= 1) s += __shfl_down(s, d, 64);
    __shared__ float ws[4];
    int lane = t & 63, w = t >> 6;
    if (lane == 0) ws[w] = s;
    __syncthreads();
    if (t == 0) {
        float tot = ws[0] + ws[1] + ws[2] + ws[3];
        float cnt = (float)(hi - lo);
        out[g] = tot / fmaxf(cnt, 1.0f) + bfc[0];
    }
}

// ---------------- launch ----------------
extern "C" void kernel_launch(void* const* d_in, const int* in_sizes, int n_in,
                              void* d_out, int out_size, void* d_ws, size_t ws_size,
                              hipStream_t stream) {
    const float* x    = (const float*)d_in[0];
    const int*   ei   = (const int*)d_in[1];     // [2, E] : row0 = src, row1 = dst
    const int*   batch= (const int*)d_in[2];
    const float* W1   = (const float*)d_in[3];
    const float* b1   = (const float*)d_in[4];
    const float* W2   = (const float*)d_in[5];
    const float* b2   = (const float*)d_in[6];
    const float* W3   = (const float*)d_in[7];
    const float* b3   = (const float*)d_in[8];
    const float* Wfc  = (const float*)d_in[9];
    const float* bfc  = (const float*)d_in[10];
    float* out = (float*)d_out;

    const int* src = ei;
    const int* dst = ei + N_EDGES;

    // carve workspace (256B-aligned)
    char* p = (char*)d_ws;
    auto carve = [&](size_t bytes) { void* r = (void*)p; p += (bytes + 255) & ~(size_t)255; return r; };
    int*    cur       = (int*)   carve(sizeof(int) * NBUCK);                              // 1.6 KB
    uint32* bbuf      = (uint32*)carve(sizeof(uint32) * (size_t)NBUCK * BCAP);            // 7.2 MB
    int*    bucketBase= (int*)   carve(sizeof(int) * (NBUCK + 1));
    float*  dinv      = (float*) carve(sizeof(float) * N_NODES);
    int*    offsets   = (int*)   carve(sizeof(int) * (N_NODES + 1));
    int*    col       = (int*)   carve(sizeof(int) * N_EDGES);
    ushort* XW        = (ushort*)carve(sizeof(short) * (size_t)N_NODES * NFEAT);
    ushort* H         = (ushort*)carve(sizeof(short) * (size_t)N_NODES * NFEAT);
    ushort* WT        = (ushort*)carve(sizeof(short) * 3 * NFEAT * NFEAT);
    float*  nodeS     = (float*) carve(sizeof(float) * N_NODES);

    const int waveNodeBlocks = (N_NODES * 64 + 255) / 256;   // 25000
    const int gemmBlocks = (N_NODES + 63) / 64;              // 1563

    hipMemsetAsync(cur, 0, sizeof(int) * NBUCK, stream);
    k_scatter<<<SC_BLOCKS, 256, 0, stream>>>(src, dst, cur, bbuf);
    k_bucketscan<<<1, 256, 0, stream>>>(cur, bucketBase, offsets);
    k_build<<<NBUCK, 256, 0, stream>>>(bbuf, cur, bucketBase, col, offsets, dinv);

    k_castw<<<(3 * NFEAT * NFEAT + 255) / 256, 256, 0, stream>>>(W1, W2, W3, WT);

    // layer 1 (cast fused into GEMM A-load)
    k_gemm_x<<<gemmBlocks, 256, 0, stream>>>(x, WT, XW, N_NODES);
    k_agg<<<waveNodeBlocks, 256, 0, stream>>>((const uint32*)XW, col, offsets, dinv, b1, (uint32*)H);
    // layer 2
    k_gemm<<<gemmBlocks, 256, 0, stream>>>(H, WT + NFEAT * NFEAT, XW, N_NODES);
    k_agg<<<waveNodeBlocks, 256, 0, stream>>>((const uint32*)XW, col, offsets, dinv, b2, (uint32*)H);
    // layer 3
    k_gemm<<<gemmBlocks, 256, 0, stream>>>(H, WT + 2 * NFEAT * NFEAT, XW, N_NODES);
    k_agg_fc<<<waveNodeBlocks, 256, 0, stream>>>((const uint32*)XW, col, offsets, dinv, b3, Wfc, nodeS);

    k_pool<<<N_GRAPHS, 256, 0, stream>>>(nodeS, batch, bfc, out);
}

// Round 12
// 392.351 us; speedup vs baseline: 1.9118x; 1.0022x over previous
//
#include <hip/hip_runtime.h>

#define N_NODES   100000
#define N_EDGES   1600000
#define NFEAT     128
#define N_GRAPHS  1024

// ---- bucketed CSR build (256-node buckets, block-local counting-sort scatter) ----
#define BSHIFT  8
#define BNODES  256
#define NBUCK   391                  // ceil(100000 / 256)
#define BCAP    4608                 // mean 4096 + 8 sigma
#define SC_EDGES 8192
#define SC_BLOCKS 196                // ceil(1.6M / 8192)

typedef unsigned int uint32;
typedef unsigned short ushort;
typedef __attribute__((ext_vector_type(8))) short short8;   // 8 bf16 (4 VGPRs)
typedef __attribute__((ext_vector_type(4))) float f32x4;

// fp32 -> bf16 bits, round-to-nearest-even (finite inputs)
__device__ inline ushort f2b(float f) {
    uint32 x = __float_as_uint(f);
    uint32 r = x + 0x7fffu + ((x >> 16) & 1u);
    return (ushort)(r >> 16);
}
__device__ inline float blo(uint32 u) { return __uint_as_float(u << 16); }
__device__ inline float bhi(uint32 u) { return __uint_as_float(u & 0xffff0000u); }

// ---------------- scatter: block-local counting sort -> burst writes, 1 atomic per (block,bin) ----------------
__global__ __launch_bounds__(256) void k_scatter(const int* __restrict__ src, const int* __restrict__ dst,
                                                 int* __restrict__ cur, uint32* __restrict__ bbuf) {
    __shared__ int hist[NBUCK];
    __shared__ int lofs[NBUCK];
    __shared__ int lcur[NBUCK];
    __shared__ int gbase[NBUCK];
    __shared__ int wsum[4];
    __shared__ uint32 sortedP[SC_EDGES];   // 32 KB
    __shared__ ushort sortedB[SC_EDGES];   // 16 KB
    int t = threadIdx.x;
    int e0 = blockIdx.x * SC_EDGES;
    int total = N_EDGES - e0; if (total > SC_EDGES) total = SC_EDGES; if (total < 0) total = 0;

    for (int i = t; i < NBUCK; i += 256) hist[i] = 0;
    __syncthreads();
    for (int i = t; i < total; i += 256)
        atomicAdd(&hist[dst[e0 + i] >> BSHIFT], 1);
    __syncthreads();
    {
        int b0 = 2 * t, b1 = 2 * t + 1;
        int h0 = (b0 < NBUCK) ? hist[b0] : 0;
        int h1 = (b1 < NBUCK) ? hist[b1] : 0;
        int ts = h0 + h1;
        int lane = t & 63, w = t >> 6;
        int inc = ts;
        #pragma unroll
        for (int d = 1; d < 64; d <<= 1) {
            int u = __shfl_up(inc, d, 64);
            if (lane >= d) inc += u;
        }
        if (lane == 63) wsum[w] = inc;
        __syncthreads();
        int wpre = 0;
        for (int i = 0; i < w; ++i) wpre += wsum[i];
        int run = wpre + inc - ts;
        if (b0 < NBUCK) {
            lofs[b0] = run; lcur[b0] = run;
            if (h0) gbase[b0] = atomicAdd(&cur[b0], h0);
        }
        if (b1 < NBUCK) {
            lofs[b1] = run + h0; lcur[b1] = run + h0;
            if (h1) gbase[b1] = atomicAdd(&cur[b1], h1);
        }
    }
    __syncthreads();
    for (int i = t; i < total; i += 256) {
        int s = src[e0 + i], d = dst[e0 + i];
        int b = d >> BSHIFT;
        int p = atomicAdd(&lcur[b], 1);
        sortedP[p] = ((uint32)(d & (BNODES - 1)) << 17) | (uint32)s;
        sortedB[p] = (ushort)b;
    }
    __syncthreads();
    for (int i = t; i < total; i += 256) {
        int b = sortedB[i];
        int addr = gbase[b] + (i - lofs[b]);
        if (addr < BCAP)
            bbuf[(size_t)b * BCAP + addr] = sortedP[i];
    }
}

// ---------------- exclusive scan of bucket totals -> bucketBase + offsets[N] ----------------
__global__ __launch_bounds__(256) void k_bucketscan(const int* __restrict__ cur, int* __restrict__ bucketBase,
                                                    int* __restrict__ offsets) {
    __shared__ int wsum[4];
    int t = threadIdx.x;
    int b0 = 2 * t, b1 = 2 * t + 1;
    int h0 = 0, h1 = 0;
    if (b0 < NBUCK) { h0 = cur[b0]; if (h0 > BCAP) h0 = BCAP; }
    if (b1 < NBUCK) { h1 = cur[b1]; if (h1 > BCAP) h1 = BCAP; }
    int ts = h0 + h1;
    int lane = t & 63, w = t >> 6;
    int inc = ts;
    #pragma unroll
    for (int d = 1; d < 64; d <<= 1) {
        int u = __shfl_up(inc, d, 64);
        if (lane >= d) inc += u;
    }
    if (lane == 63) wsum[w] = inc;
    __syncthreads();
    int wpre = 0;
    for (int i = 0; i < w; ++i) wpre += wsum[i];
    int run = wpre + inc - ts;
    if (b0 < NBUCK) bucketBase[b0] = run;
    if (b1 < NBUCK) bucketBase[b1] = run + h0;
    if (t == 255) offsets[N_NODES] = run + ts;
}

// ---------------- per-bucket counting sort -> CSR col + offsets + dinv ----------------
__global__ __launch_bounds__(256) void k_build(const uint32* __restrict__ bbuf, const int* __restrict__ cur,
                                               const int* __restrict__ bucketBase, int* __restrict__ col,
                                               int* __restrict__ offsets, float* __restrict__ dinv) {
    int b = blockIdx.x;
    __shared__ int hist[BNODES], lcur[BNODES];
    __shared__ int wsum[4];
    __shared__ int sorted[BCAP];              // 18 KB
    int t = threadIdx.x;
    int cnt = cur[b]; if (cnt > BCAP) cnt = BCAP;
    const uint32* reg = bbuf + (size_t)b * BCAP;
    hist[t] = 0;
    __syncthreads();
    for (int i = t; i < cnt; i += 256) atomicAdd(&hist[reg[i] >> 17], 1);
    __syncthreads();
    {
        int c = hist[t];
        int lane = t & 63, w = t >> 6;
        int inc = c;
        #pragma unroll
        for (int d = 1; d < 64; d <<= 1) {
            int u = __shfl_up(inc, d, 64);
            if (lane >= d) inc += u;
        }
        if (lane == 63) wsum[w] = inc;
        __syncthreads();
        int wpre = 0;
        for (int i = 0; i < w; ++i) wpre += wsum[i];
        int excl = wpre + inc - c;
        lcur[t] = excl;
        int node = (b << BSHIFT) + t;
        if (node < N_NODES) {
            offsets[node] = bucketBase[b] + excl;
            dinv[node] = rsqrtf((float)(c + 1));
        }
    }
    __syncthreads();
    for (int i = t; i < cnt; i += 256) {
        uint32 p = reg[i];
        int lp = atomicAdd(&lcur[p >> 17], 1);
        sorted[lp] = (int)(p & 0x1FFFF);
    }
    __syncthreads();
    int base = bucketBase[b];
    for (int i = t; i < cnt; i += 256) col[base + i] = sorted[i];
}

// ---------------- cast + transpose W1,W2,W3 -> WT bf16 [layer][n][k] ----------------
__global__ __launch_bounds__(256) void k_castw(const float* __restrict__ W1, const float* __restrict__ W2,
                                               const float* __restrict__ W3, ushort* __restrict__ WT) {
    int i = blockIdx.x * blockDim.x + threadIdx.x;   // 3*16384
    if (i >= 3 * NFEAT * NFEAT) return;
    int l = i >> 14;
    int j = i & 16383;
    int n = j >> 7;
    int k = j & 127;
    const float* W = (l == 0) ? W1 : (l == 1) ? W2 : W3;
    WT[i] = f2b(W[k * NFEAT + n]);   // WT[l][n*128+k] = W[k][n]
}

// ---------------- bf16 MFMA GEMM: C[M,128] = A[M,128] @ W ----------------
// 512 threads, 8 waves x 16 rows = 128 rows/block -> W staged once per 128 rows
// (2x amortization vs 64). Epilogue stages the 128x128 bf16 C-tile in LDS
// (reusing sWT, 32KB <= 34KB) -> dwordx4 coalesced stores.
#define WT_STRIDE 136
#define GEMM_EPILOGUE \
    __syncthreads(); \
    { \
        ushort* sC = sWT; \
        int colBase = lane & 15; \
        _Pragma("unroll") \
        for (int r = 0; r < 4; ++r) { \
            int lr = wave * 16 + kg * 4 + r; \
            _Pragma("unroll") \
            for (int nt = 0; nt < 8; ++nt) \
                sC[lr * NFEAT + nt * 16 + colBase] = f2b(acc[nt][r]); \
        } \
    } \
    __syncthreads(); \
    { \
        int rowBase = blockIdx.x * 128; \
        const float4* sC4 = (const float4*)sWT; \
        for (int i = t; i < 2048; i += 512) { \
            int row = i >> 4; \
            int gr = rowBase + row; \
            if (gr < M) ((float4*)(C + (size_t)gr * NFEAT))[i & 15] = sC4[i]; \
        } \
    }

__global__ __launch_bounds__(512) void k_gemm(const ushort* __restrict__ A,
                                              const ushort* __restrict__ WTl,
                                              ushort* __restrict__ C, int M) {
    __shared__ ushort sWT[NFEAT * WT_STRIDE];   // 34 KB
    int t = threadIdx.x;
    for (int i = t; i < NFEAT * 16; i += 512) {
        int n = i >> 4, c = i & 15;
        *(float4*)(sWT + n * WT_STRIDE + c * 8) = ((const float4*)WTl)[i];
    }
    int wave = t >> 6, lane = t & 63;
    int m0 = blockIdx.x * 128 + wave * 16;
    int mRow = m0 + (lane & 15);
    if (mRow >= M) mRow = M - 1;
    int kg = lane >> 4;
    const short8* Ap = (const short8*)(A + (size_t)mRow * NFEAT + kg * 8);
    short8 a0 = Ap[0];
    short8 a1 = Ap[4];
    short8 a2 = Ap[8];
    short8 a3 = Ap[12];
    __syncthreads();

    f32x4 acc[8];
    #pragma unroll
    for (int nt = 0; nt < 8; ++nt) acc[nt] = (f32x4){0.f, 0.f, 0.f, 0.f};

    #pragma unroll
    for (int nt = 0; nt < 8; ++nt) {
        int n = nt * 16 + (lane & 15);
        const short8* Bp = (const short8*)(sWT + n * WT_STRIDE + kg * 8);
        short8 b0 = Bp[0];
        short8 b1 = Bp[4];
        short8 b2 = Bp[8];
        short8 b3 = Bp[12];
        acc[nt] = __builtin_amdgcn_mfma_f32_16x16x32_bf16(a0, b0, acc[nt], 0, 0, 0);
        acc[nt] = __builtin_amdgcn_mfma_f32_16x16x32_bf16(a1, b1, acc[nt], 0, 0, 0);
        acc[nt] = __builtin_amdgcn_mfma_f32_16x16x32_bf16(a2, b2, acc[nt], 0, 0, 0);
        acc[nt] = __builtin_amdgcn_mfma_f32_16x16x32_bf16(a3, b3, acc[nt], 0, 0, 0);
    }
    GEMM_EPILOGUE
}

// ---------------- same GEMM but A is fp32 (layer 1: fuses the x->bf16 cast) ----------------
__device__ inline short8 cvt8(const float* p) {
    float4 v0 = ((const float4*)p)[0];
    float4 v1 = ((const float4*)p)[1];
    short8 r;
    r[0] = (short)f2b(v0.x); r[1] = (short)f2b(v0.y);
    r[2] = (short)f2b(v0.z); r[3] = (short)f2b(v0.w);
    r[4] = (short)f2b(v1.x); r[5] = (short)f2b(v1.y);
    r[6] = (short)f2b(v1.z); r[7] = (short)f2b(v1.w);
    return r;
}

__global__ __launch_bounds__(512) void k_gemm_x(const float* __restrict__ A,
                                                const ushort* __restrict__ WTl,
                                                ushort* __restrict__ C, int M) {
    __shared__ ushort sWT[NFEAT * WT_STRIDE];   // 34 KB
    int t = threadIdx.x;
    for (int i = t; i < NFEAT * 16; i += 512) {
        int n = i >> 4, c = i & 15;
        *(float4*)(sWT + n * WT_STRIDE + c * 8) = ((const float4*)WTl)[i];
    }
    int wave = t >> 6, lane = t & 63;
    int m0 = blockIdx.x * 128 + wave * 16;
    int mRow = m0 + (lane & 15);
    if (mRow >= M) mRow = M - 1;
    int kg = lane >> 4;
    const float* Ap = A + (size_t)mRow * NFEAT + kg * 8;
    short8 a0 = cvt8(Ap);
    short8 a1 = cvt8(Ap + 32);
    short8 a2 = cvt8(Ap + 64);
    short8 a3 = cvt8(Ap + 96);
    __syncthreads();

    f32x4 acc[8];
    #pragma unroll
    for (int nt = 0; nt < 8; ++nt) acc[nt] = (f32x4){0.f, 0.f, 0.f, 0.f};

    #pragma unroll
    for (int nt = 0; nt < 8; ++nt) {
        int n = nt * 16 + (lane & 15);
        const short8* Bp = (const short8*)(sWT + n * WT_STRIDE + kg * 8);
        short8 b0 = Bp[0];
        short8 b1 = Bp[4];
        short8 b2 = Bp[8];
        short8 b3 = Bp[12];
        acc[nt] = __builtin_amdgcn_mfma_f32_16x16x32_bf16(a0, b0, acc[nt], 0, 0, 0);
        acc[nt] = __builtin_amdgcn_mfma_f32_16x16x32_bf16(a1, b1, acc[nt], 0, 0, 0);
        acc[nt] = __builtin_amdgcn_mfma_f32_16x16x32_bf16(a2, b2, acc[nt], 0, 0, 0);
        acc[nt] = __builtin_amdgcn_mfma_f32_16x16x32_bf16(a3, b3, acc[nt], 0, 0, 0);
    }
    GEMM_EPILOGUE
}

// ---------------- aggregation core: 4 edges per uint4 gather instruction ----------------
#define AGG_BODY4 \
    float dn = dinv[n]; \
    int half = lane >> 4; \
    int fl = lane & 15; \
    const uint4* XW4 = (const uint4*)XWu; \
    uint4 sv = XW4[(size_t)n * 16 + fl]; \
    float ws = (half == 0) ? dn * dn : 0.f; \
    float a0 = ws * blo(sv.x), a1 = ws * bhi(sv.x); \
    float a2 = ws * blo(sv.y), a3 = ws * bhi(sv.y); \
    float a4 = ws * blo(sv.z), a5 = ws * bhi(sv.z); \
    float a6 = ws * blo(sv.w), a7 = ws * bhi(sv.w); \
    int e0 = off[n], e1 = off[n + 1]; \
    for (int base = e0; base < e1; base += 64) { \
        int len = e1 - base; if (len > 64) len = 64; \
        int cm = (lane < len) ? col[base + lane] : 0; \
        float wm = (lane < len) ? dn * dinv[cm] : 0.f; \
        int j = 0; \
        for (; j + 16 <= len; j += 16) { \
            uint4 u[4]; float w[4]; \
            _Pragma("unroll") \
            for (int p = 0; p < 4; ++p) { \
                int idx = j + 4 * p + half; \
                int cc = __shfl(cm, idx, 64); \
                w[p] = __shfl(wm, idx, 64); \
                u[p] = XW4[(size_t)cc * 16 + fl]; \
            } \
            _Pragma("unroll") \
            for (int p = 0; p < 4; ++p) { \
                a0 = fmaf(w[p], blo(u[p].x), a0); a1 = fmaf(w[p], bhi(u[p].x), a1); \
                a2 = fmaf(w[p], blo(u[p].y), a2); a3 = fmaf(w[p], bhi(u[p].y), a3); \
                a4 = fmaf(w[p], blo(u[p].z), a4); a5 = fmaf(w[p], bhi(u[p].z), a5); \
                a6 = fmaf(w[p], blo(u[p].w), a6); a7 = fmaf(w[p], bhi(u[p].w), a7); \
            } \
        } \
        for (; j < len; j += 4) { \
            int rem = len - j; \
            int idx = j + ((half < rem) ? half : 0); \
            int cc = __shfl(cm, idx, 64); \
            float ww = __shfl(wm, idx, 64); \
            if (half >= rem) ww = 0.f; \
            uint4 u = XW4[(size_t)cc * 16 + fl]; \
            a0 = fmaf(ww, blo(u.x), a0); a1 = fmaf(ww, bhi(u.x), a1); \
            a2 = fmaf(ww, blo(u.y), a2); a3 = fmaf(ww, bhi(u.y), a3); \
            a4 = fmaf(ww, blo(u.z), a4); a5 = fmaf(ww, bhi(u.z), a5); \
            a6 = fmaf(ww, blo(u.w), a6); a7 = fmaf(ww, bhi(u.w), a7); \
        } \
    } \
    a0 += __shfl_xor(a0, 32, 64); a0 += __shfl_xor(a0, 16, 64); \
    a1 += __shfl_xor(a1, 32, 64); a1 += __shfl_xor(a1, 16, 64); \
    a2 += __shfl_xor(a2, 32, 64); a2 += __shfl_xor(a2, 16, 64); \
    a3 += __shfl_xor(a3, 32, 64); a3 += __shfl_xor(a3, 16, 64); \
    a4 += __shfl_xor(a4, 32, 64); a4 += __shfl_xor(a4, 16, 64); \
    a5 += __shfl_xor(a5, 32, 64); a5 += __shfl_xor(a5, 16, 64); \
    a6 += __shfl_xor(a6, 32, 64); a6 += __shfl_xor(a6, 16, 64); \
    a7 += __shfl_xor(a7, 32, 64); a7 += __shfl_xor(a7, 16, 64);

__global__ __launch_bounds__(256) void k_agg(const uint32* __restrict__ XWu, const int* __restrict__ col,
                                             const int* __restrict__ off, const float* __restrict__ dinv,
                                             const float* __restrict__ bias, uint32* __restrict__ Hu) {
    int wid = (blockIdx.x * blockDim.x + threadIdx.x) >> 6;
    int lane = threadIdx.x & 63;
    if (wid >= N_NODES) return;
    int n = wid;
    AGG_BODY4
    if (half == 0) {
        float4 bb0 = ((const float4*)bias)[2 * fl];
        float4 bb1 = ((const float4*)bias)[2 * fl + 1];
        float r0 = fmaxf(a0 + bb0.x, 0.f), r1 = fmaxf(a1 + bb0.y, 0.f);
        float r2 = fmaxf(a2 + bb0.z, 0.f), r3 = fmaxf(a3 + bb0.w, 0.f);
        float r4 = fmaxf(a4 + bb1.x, 0.f), r5 = fmaxf(a5 + bb1.y, 0.f);
        float r6 = fmaxf(a6 + bb1.z, 0.f), r7 = fmaxf(a7 + bb1.w, 0.f);
        uint4 o;
        o.x = (uint32)f2b(r0) | ((uint32)f2b(r1) << 16);
        o.y = (uint32)f2b(r2) | ((uint32)f2b(r3) << 16);
        o.z = (uint32)f2b(r4) | ((uint32)f2b(r5) << 16);
        o.w = (uint32)f2b(r6) | ((uint32)f2b(r7) << 16);
        ((uint4*)Hu)[(size_t)n * 16 + fl] = o;
    }
}

// ---------------- layer-3 aggregation + relu + FC dot -> per-node scalar ----------------
__global__ __launch_bounds__(256) void k_agg_fc(const uint32* __restrict__ XWu, const int* __restrict__ col,
                                                const int* __restrict__ off, const float* __restrict__ dinv,
                                                const float* __restrict__ bias, const float* __restrict__ Wfc,
                                                float* __restrict__ nodeS) {
    int wid = (blockIdx.x * blockDim.x + threadIdx.x) >> 6;
    int lane = threadIdx.x & 63;
    if (wid >= N_NODES) return;
    int n = wid;
    AGG_BODY4
    float4 bb0 = ((const float4*)bias)[2 * fl];
    float4 bb1 = ((const float4*)bias)[2 * fl + 1];
    float4 wf0 = ((const float4*)Wfc)[2 * fl];
    float4 wf1 = ((const float4*)Wfc)[2 * fl + 1];
    float s = fmaxf(a0 + bb0.x, 0.f) * wf0.x + fmaxf(a1 + bb0.y, 0.f) * wf0.y
            + fmaxf(a2 + bb0.z, 0.f) * wf0.z + fmaxf(a3 + bb0.w, 0.f) * wf0.w
            + fmaxf(a4 + bb1.x, 0.f) * wf1.x + fmaxf(a5 + bb1.y, 0.f) * wf1.y
            + fmaxf(a6 + bb1.z, 0.f) * wf1.z + fmaxf(a7 + bb1.w, 0.f) * wf1.w;
    s += __shfl_xor(s, 8, 64);
    s += __shfl_xor(s, 4, 64);
    s += __shfl_xor(s, 2, 64);
    s += __shfl_xor(s, 1, 64);
    if (lane == 0) nodeS[n] = s;
}

// ---------------- segment mean over sorted batch + bias (one block per graph) ----------------
__device__ inline int lower_bound_dev(const int* a, int n, int key) {
    int lo = 0, hi = n;
    while (lo < hi) {
        int mid = (lo + hi) >> 1;
        if (a[mid] < key) lo = mid + 1; else hi = mid;
    }
    return lo;
}

__global__ __launch_bounds__(256) void k_pool(const float* __restrict__ nodeS, const int* __restrict__ batch,
                                              const float* __restrict__ bfc, float* __restrict__ out) {
    int g = blockIdx.x;
    int t = threadIdx.x;
    int lo = lower_bound_dev(batch, N_NODES, g);
    int hi = lower_bound_dev(batch, N_NODES, g + 1);
    float s = 0.f;
    for (int i = lo + t; i < hi; i += 256) s += nodeS[i];
    for (int d = 32; d > 0; d >>= 1) s += __shfl_down(s, d, 64);
    __shared__ float ws[4];
    int lane = t & 63, w = t >> 6;
    if (lane == 0) ws[w] = s;
    __syncthreads();
    if (t == 0) {
        float tot = ws[0] + ws[1] + ws[2] + ws[3];
        float cnt = (float)(hi - lo);
        out[g] = tot / fmaxf(cnt, 1.0f) + bfc[0];
    }
}

// ---------------- launch ----------------
extern "C" void kernel_launch(void* const* d_in, const int* in_sizes, int n_in,
                              void* d_out, int out_size, void* d_ws, size_t ws_size,
                              hipStream_t stream) {
    const float* x    = (const float*)d_in[0];
    const int*   ei   = (const int*)d_in[1];     // [2, E] : row0 = src, row1 = dst
    const int*   batch= (const int*)d_in[2];
    const float* W1   = (const float*)d_in[3];
    const float* b1   = (const float*)d_in[4];
    const float* W2   = (const float*)d_in[5];
    const float* b2   = (const float*)d_in[6];
    const float* W3   = (const float*)d_in[7];
    const float* b3   = (const float*)d_in[8];
    const float* Wfc  = (const float*)d_in[9];
    const float* bfc  = (const float*)d_in[10];
    float* out = (float*)d_out;

    const int* src = ei;
    const int* dst = ei + N_EDGES;

    // carve workspace (256B-aligned)
    char* p = (char*)d_ws;
    auto carve = [&](size_t bytes) { void* r = (void*)p; p += (bytes + 255) & ~(size_t)255; return r; };
    int*    cur       = (int*)   carve(sizeof(int) * NBUCK);                              // 1.6 KB
    uint32* bbuf      = (uint32*)carve(sizeof(uint32) * (size_t)NBUCK * BCAP);            // 7.2 MB
    int*    bucketBase= (int*)   carve(sizeof(int) * (NBUCK + 1));
    float*  dinv      = (float*) carve(sizeof(float) * N_NODES);
    int*    offsets   = (int*)   carve(sizeof(int) * (N_NODES + 1));
    int*    col       = (int*)   carve(sizeof(int) * N_EDGES);
    ushort* XW        = (ushort*)carve(sizeof(short) * (size_t)N_NODES * NFEAT);
    ushort* H         = (ushort*)carve(sizeof(short) * (size_t)N_NODES * NFEAT);
    ushort* WT        = (ushort*)carve(sizeof(short) * 3 * NFEAT * NFEAT);
    float*  nodeS     = (float*) carve(sizeof(float) * N_NODES);

    const int waveNodeBlocks = (N_NODES * 64 + 255) / 256;   // 25000
    const int gemmBlocks = (N_NODES + 127) / 128;            // 782

    hipMemsetAsync(cur, 0, sizeof(int) * NBUCK, stream);
    k_scatter<<<SC_BLOCKS, 256, 0, stream>>>(src, dst, cur, bbuf);
    k_bucketscan<<<1, 256, 0, stream>>>(cur, bucketBase, offsets);
    k_build<<<NBUCK, 256, 0, stream>>>(bbuf, cur, bucketBase, col, offsets, dinv);

    k_castw<<<(3 * NFEAT * NFEAT + 255) / 256, 256, 0, stream>>>(W1, W2, W3, WT);

    // layer 1 (cast fused into GEMM A-load)
    k_gemm_x<<<gemmBlocks, 512, 0, stream>>>(x, WT, XW, N_NODES);
    k_agg<<<waveNodeBlocks, 256, 0, stream>>>((const uint32*)XW, col, offsets, dinv, b1, (uint32*)H);
    // layer 2
    k_gemm<<<gemmBlocks, 512, 0, stream>>>(H, WT + NFEAT * NFEAT, XW, N_NODES);
    k_agg<<<waveNodeBlocks, 256, 0, stream>>>((const uint32*)XW, col, offsets, dinv, b2, (uint32*)H);
    // layer 3
    k_gemm<<<gemmBlocks, 512, 0, stream>>>(H, WT + 2 * NFEAT * NFEAT, XW, N_NODES);
    k_agg_fc<<<waveNodeBlocks, 256, 0, stream>>>((const uint32*)XW, col, offsets, dinv, b3, Wfc, nodeS);

    k_pool<<<N_GRAPHS, 256, 0, stream>>>(nodeS, batch, bfc, out);
}